// Round 15
// baseline (875.028 us; speedup 1.0000x reference)
//
#include <hip/hip_runtime.h>

typedef unsigned short u16;
typedef unsigned int u32;
typedef __attribute__((ext_vector_type(8))) __bf16 bf16x8;
typedef __attribute__((ext_vector_type(4))) float f32x4;
typedef __attribute__((ext_vector_type(16))) float f32x16;

#define CLEN 1664
#define SEQL 4992
#define NHEADS 16
#define HD 128
#define HID 2048
#define KVD 512
#define SCALE 0.08838834764831845f
#define SCLOG2E 0.12752615142058843f  // SCALE * log2(e)

__device__ __forceinline__ u16 f2bf(float f) {
  union { float f; u32 u; } v; v.f = f;
  u32 u = v.u;
  return (u16)((u + 0x7FFFu + ((u >> 16) & 1u)) >> 16);
}
__device__ __forceinline__ float bf2f(u16 h) {
  union { u32 u; float f; } v; v.u = (u32)h << 16;
  return v.f;
}
__device__ __forceinline__ f32x4 mfma16(bf16x8 a, bf16x8 b, f32x4 c) {
  return __builtin_amdgcn_mfma_f32_16x16x32_bf16(a, b, c, 0, 0, 0);
}
__device__ __forceinline__ f32x16 mfma32(bf16x8 a, bf16x8 b, f32x16 c) {
  return __builtin_amdgcn_mfma_f32_32x32x16_bf16(a, b, c, 0, 0, 0);
}
__device__ __forceinline__ u32 cvtpk(float lo, float hi) {
  u32 r;
  asm("v_cvt_pk_bf16_f32 %0, %1, %2" : "=v"(r) : "v"(lo), "v"(hi));
  return r;
}
__device__ __forceinline__ float exp2v(float x) {
  float r;
  asm("v_exp_f32 %0, %1" : "=v"(r) : "v"(x));
  return r;
}
__device__ __forceinline__ void gload_lds16(const u16* g, u16* l) {
  __builtin_amdgcn_global_load_lds((const __attribute__((address_space(1))) void*)g,
                                   (__attribute__((address_space(3))) void*)l, 16, 0, 0);
}

// ---------------- fused f32 -> bf16 convert (5 regions, 1 launch) ----------
#define CVT_Q0 2555904   // hidden  (10223616/4)
#define CVT_Q1 1048576   // Wq
#define CVT_Q2 262144    // Wk
#define CVT_Q3 262144    // Wv
#define CVT_Q4 1048576   // Wo
__device__ __forceinline__ void cvt4(const float* s, u16* d, int q) {
  float4 v = *(const float4*)(s + (size_t)q * 4);
  uint2 p;
  p.x = (u32)f2bf(v.x) | ((u32)f2bf(v.y) << 16);
  p.y = (u32)f2bf(v.z) | ((u32)f2bf(v.w) << 16);
  *(uint2*)(d + (size_t)q * 4) = p;
}
__global__ void cvt_all_kernel(const float* __restrict__ hidden, const float* __restrict__ Wq,
                               const float* __restrict__ Wk, const float* __restrict__ Wv,
                               const float* __restrict__ Wo, u16* __restrict__ h_bf,
                               u16* __restrict__ Wqkv, u16* __restrict__ Wo_bf) {
  int q = blockIdx.x * blockDim.x + threadIdx.x;
  if (q < CVT_Q0) { cvt4(hidden, h_bf, q); return; }
  q -= CVT_Q0;
  if (q < CVT_Q1) { cvt4(Wq, Wqkv, q); return; }
  q -= CVT_Q1;
  if (q < CVT_Q2) { cvt4(Wk, Wqkv + 2048 * 2048, q); return; }
  q -= CVT_Q2;
  if (q < CVT_Q3) { cvt4(Wv, Wqkv + 2560 * 2048, q); return; }
  q -= CVT_Q3;
  if (q < CVT_Q4) cvt4(Wo, Wo_bf, q);
}

// ---------------- fused RoPE (4 regions, 1 launch); Q paths pre-scaled -----
#define RP_N0 1277952  // qa : 4992*256
#define RP_N1 851968   // qb : 3328*256
#define RP_N2 425984   // qf : 1664*256
#define RP_N3 319488   // k  : 4992*64
__device__ __forceinline__ void rope8(const u16* __restrict__ src, u16* __restrict__ dst,
                                      const float* __restrict__ ctab, const float* __restrict__ stab,
                                      int s, int dstrow, int col, int rowlen, int pid, float scl) {
  const int dh = col & 127;
  const bool hih = dh >= 64;
  const u16* rowp = src + (size_t)s * rowlen;
  union { uint4 u; u16 h[8]; } X, P, O;
  X.u = *(const uint4*)(rowp + col);
  P.u = *(const uint4*)(rowp + col + (hih ? -64 : 64));
  const float* cp = ctab + pid * 128 + dh;
  const float* sp = stab + pid * 128 + dh;
#pragma unroll
  for (int j = 0; j < 8; ++j) {
    float v = bf2f(X.h[j]) * cp[j] + (hih ? bf2f(P.h[j]) : -bf2f(P.h[j])) * sp[j];
    O.h[j] = f2bf(v * scl);
  }
  *(uint4*)(dst + (size_t)dstrow * rowlen + col) = O.u;
}
__global__ void rope_all_kernel(const u16* __restrict__ q_tmp, const u16* __restrict__ k_tmp,
                                u16* __restrict__ qa, u16* __restrict__ qb, u16* __restrict__ qf,
                                u16* __restrict__ k_bf, const float* __restrict__ q_cos,
                                const float* __restrict__ q_sin, const float* __restrict__ qc_cos,
                                const float* __restrict__ qc_sin, const float* __restrict__ k_cos,
                                const float* __restrict__ k_sin) {
  int o = blockIdx.x * blockDim.x + threadIdx.x;
  if (o < RP_N0) {
    int r = o >> 8, col = (o & 255) * 8;
    rope8(q_tmp, qa, q_cos, q_sin, r, r, col, 2048, r % CLEN, SCLOG2E);
    return;
  }
  o -= RP_N0;
  if (o < RP_N1) {
    int r = o >> 8, col = (o & 255) * 8, s = CLEN + r;
    rope8(q_tmp, qb, qc_cos, qc_sin, s, r, col, 2048, s % CLEN, SCLOG2E);
    return;
  }
  o -= RP_N1;
  if (o < RP_N2) {
    int r = o >> 8, col = (o & 255) * 8, s = 2 * CLEN + r;
    rope8(q_tmp, qf, qc_cos, qc_sin, s, r, col, 2048, CLEN - 1, SCLOG2E);
    return;
  }
  o -= RP_N2;
  if (o < RP_N3) {
    int r = o >> 6, col = (o & 63) * 8;
    rope8(k_tmp, k_bf, k_cos, k_sin, r, r, col, 512, r, 1.0f);
  }
}

// ---------------- fused QKV GEMM (1D grid, XCD-swizzled) -------------------
__global__ __launch_bounds__(256) void gemm_qkv(const u16* __restrict__ A, const u16* __restrict__ B,
                                                u16* __restrict__ q_tmp, u16* __restrict__ k_tmp,
                                                u16* __restrict__ vT) {
  __shared__ __align__(16) u16 Al[128 * 64];
  __shared__ __align__(16) u16 Bl[128 * 64];
  const int K = HID;
  const int t = threadIdx.x;
  const int lane = t & 63, wid = t >> 6;
  const int g = lane >> 4, c = lane & 15;
  const int wr = wid >> 1, wc = wid & 1;
  const int bid = blockIdx.x;                      // 936 = 39 x 24, 936%8==0
  const int wg = (bid & 7) * 117 + (bid >> 3);     // XCD-contiguous chunks
  const int m0 = (wg % 39) * 128, n0 = (wg / 39) * 128;

  f32x4 acc[4][4];
#pragma unroll
  for (int m = 0; m < 4; ++m)
#pragma unroll
    for (int n = 0; n < 4; ++n) acc[m][n] = (f32x4){0.f, 0.f, 0.f, 0.f};

  const int scol = (t & 7) * 8;
  for (int k0 = 0; k0 < K; k0 += 64) {
    __syncthreads();
#pragma unroll
    for (int i = 0; i < 4; ++i) {
      const int r = i * 32 + (t >> 3);
      gload_lds16(A + (size_t)(m0 + r) * K + k0 + scol, Al + i * 2048 + wid * 512);
      gload_lds16(B + (size_t)(n0 + r) * K + k0 + scol, Bl + i * 2048 + wid * 512);
    }
    __syncthreads();
#pragma unroll
    for (int kk = 0; kk < 2; ++kk) {
      bf16x8 af[4], bfr[4];
#pragma unroll
      for (int m = 0; m < 4; ++m)
        af[m] = *(const bf16x8*)(Al + (wr * 64 + m * 16 + c) * 64 + kk * 32 + g * 8);
#pragma unroll
      for (int n = 0; n < 4; ++n)
        bfr[n] = *(const bf16x8*)(Bl + (wc * 64 + n * 16 + c) * 64 + kk * 32 + g * 8);
#pragma unroll
      for (int m = 0; m < 4; ++m)
#pragma unroll
        for (int n = 0; n < 4; ++n)
          acc[m][n] = mfma16(af[m], bfr[n], acc[m][n]);
    }
  }
#pragma unroll
  for (int m = 0; m < 4; ++m)
#pragma unroll
    for (int n = 0; n < 4; ++n)
#pragma unroll
      for (int j = 0; j < 4; ++j) {
        const int row = m0 + wr * 64 + m * 16 + 4 * g + j;
        const int col = n0 + wc * 64 + n * 16 + c;
        const float v = acc[m][n][j];
        if (n0 < 2048)       q_tmp[(size_t)row * 2048 + col] = f2bf(v);
        else if (n0 < 2560)  k_tmp[(size_t)row * 512 + (col - 2048)] = f2bf(v);
        else                 vT[(size_t)(col - 2560) * SEQL + row] = f2bf(v);
      }
}

// ---------------- O-projection GEMM (1D grid, XCD-swizzled), f32 out -------
__global__ __launch_bounds__(256) void gemm_o(const u16* __restrict__ A, const u16* __restrict__ B,
                                              float* __restrict__ Cf) {
  __shared__ __align__(16) u16 Al[128 * 64];
  __shared__ __align__(16) u16 Bl[128 * 64];
  const int K = HID, N = HID;
  const int t = threadIdx.x;
  const int lane = t & 63, wid = t >> 6;
  const int g = lane >> 4, c = lane & 15;
  const int wr = wid >> 1, wc = wid & 1;
  const int bid = blockIdx.x;                      // 624 = 39 x 16, 624%8==0
  const int wg = (bid & 7) * 78 + (bid >> 3);
  const int m0 = (wg % 39) * 128, n0 = (wg / 39) * 128;

  f32x4 acc[4][4];
#pragma unroll
  for (int m = 0; m < 4; ++m)
#pragma unroll
    for (int n = 0; n < 4; ++n) acc[m][n] = (f32x4){0.f, 0.f, 0.f, 0.f};

  const int scol = (t & 7) * 8;
  for (int k0 = 0; k0 < K; k0 += 64) {
    __syncthreads();
#pragma unroll
    for (int i = 0; i < 4; ++i) {
      const int r = i * 32 + (t >> 3);
      gload_lds16(A + (size_t)(m0 + r) * K + k0 + scol, Al + i * 2048 + wid * 512);
      gload_lds16(B + (size_t)(n0 + r) * K + k0 + scol, Bl + i * 2048 + wid * 512);
    }
    __syncthreads();
#pragma unroll
    for (int kk = 0; kk < 2; ++kk) {
      bf16x8 af[4], bfr[4];
#pragma unroll
      for (int m = 0; m < 4; ++m)
        af[m] = *(const bf16x8*)(Al + (wr * 64 + m * 16 + c) * 64 + kk * 32 + g * 8);
#pragma unroll
      for (int n = 0; n < 4; ++n)
        bfr[n] = *(const bf16x8*)(Bl + (wc * 64 + n * 16 + c) * 64 + kk * 32 + g * 8);
#pragma unroll
      for (int m = 0; m < 4; ++m)
#pragma unroll
        for (int n = 0; n < 4; ++n)
          acc[m][n] = mfma16(af[m], bfr[n], acc[m][n]);
    }
  }
#pragma unroll
  for (int m = 0; m < 4; ++m)
#pragma unroll
    for (int n = 0; n < 4; ++n)
#pragma unroll
      for (int j = 0; j < 4; ++j) {
        const int row = m0 + wr * 64 + m * 16 + 4 * g + j;
        const int col = n0 + wc * 64 + n * 16 + c;
        Cf[(size_t)row * N + col] = acc[m][n][j];
      }
}

// ---------------- barrier-free direct-L2 partial-attention kernel ----------
// grid 672, 512 threads. r14's stream-to-XCD static placement (keeps KV hot in
// the local L2). NO LDS staging, NO barriers: each wave reads K (b128) and V
// (b64) fragments directly from L2 and runs its own kv loop — per-wave-exact
// causal bounds, latency hidden by independent-wave TLP (m114).
__global__ __launch_bounds__(512) void attn_kernel(
    const u16* __restrict__ qa, const u16* __restrict__ qbuf, const u16* __restrict__ qf,
    const u16* __restrict__ kbf, const u16* __restrict__ vT,
    u16* __restrict__ Opart, float* __restrict__ lseout) {
  __shared__ __align__(16) u16 scr_all[8 * 4096];  // per-wave 32x128 epilogue scratch

  const int t = threadIdx.x, wid = t >> 6, lane = t & 63;
  const int ql = lane & 31, hi = lane >> 5;

  // ---- stream-affine static part decode (r14, proven) ----
  const int b = blockIdx.x;
  const int x = b & 7;                   // XCD (assumed b%8 round-robin)
  const int j = b >> 3;                  // 0..83 within this XCD
  const int k = x >> 1;                  // kv head group owned by this XCD pair
  int chunk, seg, qb, head_lo;
  if ((x & 1) == 0) {                    // stream (k, seg0)
    if (j < 56) {                        // fulls (1,0),(2,0): 26 tiles
      chunk = (j < 28) ? 1 : 2; seg = 0;
      const int jj = j % 28;
      qb = jj >> 2; head_lo = jj & 3;
    } else {                             // causal chunk0 (reads seg0), qb desc
      const int jj = j - 56;
      chunk = 0; seg = 0;
      qb = 6 - (jj >> 2); head_lo = jj & 3;
    }
  } else {                               // streams (k,seg1) then (k,seg2)
    if (j < 28) {                        // full (2,1): 26 tiles
      chunk = 2; seg = 1;
      qb = j >> 2; head_lo = j & 3;
    } else if (j < 56) {                 // causal chunk1 (reads seg1), qb desc
      const int jj = j - 28;
      chunk = 1; seg = 1;
      qb = 6 - (jj >> 2); head_lo = jj & 3;
    } else {                             // causal chunk2 (reads seg2), qb desc
      const int jj = j - 56;
      chunk = 2; seg = 2;
      qb = 6 - (jj >> 2); head_lo = jj & 3;
    }
  }
  const int head = k * 4 + head_lo;
  const bool causal = (seg == chunk);
  const int slot = causal ? 0 : ((chunk - seg == 1) ? 1 : 2);
  const int kvh = k;
  const int kvbase = seg * CLEN;
  const int qcb = qb * 256 + wid * 32;
  const int qpos = qcb + ql;
  const bool wact = qcb < CLEN;          // qb==6 upper waves idle
  // per-wave tile bound (tighter than block-granular for causal)
  const int ntw = wact ? (causal ? ((qcb >> 6) + 1) : 26) : 0;

  const u16* qp; int qoff;
  if (causal)                { qp = qa;   qoff = 0; }
  else if (chunk - seg == 1) { qp = qbuf; qoff = CLEN; }
  else                       { qp = qf;   qoff = 2 * CLEN; }

  bf16x8 aq[8];
  {
    const int qrow = wact ? (chunk * CLEN + qpos - qoff) : 0;
    const u16* qptr = qp + (size_t)qrow * HID + head * HD + hi * 8;
#pragma unroll
    for (int ck = 0; ck < 8; ++ck) aq[ck] = *(const bf16x8*)(qptr + ck * 16);
  }

  float l_r = 0.f;
  f32x16 oacc[4];
#pragma unroll
  for (int db = 0; db < 4; ++db)
#pragma unroll
    for (int r = 0; r < 16; ++r) oacc[db][r] = 0.f;

  const u16* kbase = kbf + (size_t)kvbase * KVD + kvh * HD;
  const u16* vbase = vT + (size_t)(kvh * HD) * SEQL + kvbase;

  for (int kt = 0; kt < ntw; ++kt) {
    const int kv0 = kt * 64;
#pragma unroll
    for (int s = 0; s < 2; ++s) {
      if (causal && kv0 + 32 * s > qcb + 31) break;
      // ---- QK^T (swapped): K fragments straight from L2 ----
      const u16* krow = kbase + (size_t)(kv0 + 32 * s + ql) * KVD;
      bf16x8 kb[8];
#pragma unroll
      for (int ck = 0; ck < 8; ++ck)
        kb[ck] = *(const bf16x8*)(krow + (2 * ck + hi) * 8);
      f32x16 sacc;
#pragma unroll
      for (int r = 0; r < 16; ++r) sacc[r] = 0.f;
      __builtin_amdgcn_s_setprio(1);
#pragma unroll
      for (int ck = 0; ck < 8; ++ck) sacc = mfma32(kb[ck], aq[ck], sacc);
      __builtin_amdgcn_s_setprio(0);
      // ---- softmax, fixed m=0; scores pre-scaled by SCALE*log2e -> 2^x ----
      const int thr = qpos - kv0 - 32 * s - 4 * hi;
      float e[16];
      float rs = 0.f;
#pragma unroll
      for (int r = 0; r < 16; ++r) {
        const int crow_r = (r & 3) + 8 * (r >> 2);
        float ev = (causal && crow_r > thr) ? -1e30f : sacc[r];
        e[r] = exp2v(ev);
        rs += e[r];
      }
      rs += __shfl_xor(rs, 32);
      l_r += rs;
      u32 wp[8];
#pragma unroll
      for (int j2 = 0; j2 < 8; ++j2) wp[j2] = cvtpk(e[2 * j2], e[2 * j2 + 1]);
      // ---- PV: V fragments straight from L2 ----
      __builtin_amdgcn_s_setprio(1);
#pragma unroll
      for (int ks = 0; ks < 2; ++ks) {
        union { uint4 u; bf16x8 v; } pa;
        pa.u.x = wp[4 * ks]; pa.u.y = wp[4 * ks + 1];
        pa.u.z = wp[4 * ks + 2]; pa.u.w = wp[4 * ks + 3];
        const int g4a = 8 * s + 4 * ks + hi;
#pragma unroll
        for (int db = 0; db < 4; ++db) {
          const u16* vrowp = vbase + (size_t)(32 * db + ql) * SEQL + kv0;
          const uint2 v0 = *(const uint2*)(vrowp + g4a * 4);
          const uint2 v1 = *(const uint2*)(vrowp + g4a * 4 + 8);
          union { uint4 u; bf16x8 v; } bv;
          bv.u.x = v0.x; bv.u.y = v0.y; bv.u.z = v1.x; bv.u.w = v1.y;
          oacc[db] = mfma32(pa.v, bv.v, oacc[db]);
        }
      }
      __builtin_amdgcn_s_setprio(0);
    }
  }
  // ---- epilogue: scale, transpose via per-wave LDS scratch, 256B rows ------
  if (wact) {
    const float linv = 1.0f / l_r;
    u16* scr = scr_all + wid * 4096;
#pragma unroll
    for (int r = 0; r < 16; ++r) {
      const int rrow = (r & 3) + 8 * (r >> 2) + 4 * hi;
      const float li = __shfl(linv, rrow);
#pragma unroll
      for (int db = 0; db < 4; ++db)
        scr[rrow * 128 + db * 32 + ql] = f2bf(oacc[db][r] * li);
    }
    asm volatile("s_waitcnt lgkmcnt(0)" ::: "memory");
    const int rcol = lane & 15;
#pragma unroll
    for (int p = 0; p < 8; ++p) {
      const int row = p * 4 + (lane >> 4);
      uint4 v = *(const uint4*)(scr + row * 128 + rcol * 8);
      const size_t grow = (size_t)(chunk * CLEN + qcb + row);
      *(uint4*)(Opart + ((size_t)slot * SEQL + grow) * HID + head * HD + rcol * 8) = v;
    }
    if (hi == 0)
      lseout[((size_t)slot * NHEADS + head) * SEQL + chunk * CLEN + qcb + ql] = __logf(l_r);
  }
}

// ---------------- merge partials (softmax over lse) ------------------------
__global__ void merge_kernel(const u16* __restrict__ Opart, const float* __restrict__ lse,
                             u16* __restrict__ amrg) {
  const int idx = blockIdx.x * blockDim.x + threadIdx.x;  // 4992*256 threads
  const int row = idx >> 8;
  const int col = (idx & 255) * 8;
  const int head = col >> 7;
  const int np = row / CLEN + 1;
  float ls[3];
  float mx = -1e30f;
  for (int i = 0; i < np; ++i) {
    ls[i] = lse[((size_t)i * NHEADS + head) * SEQL + row];
    mx = fmaxf(mx, ls[i]);
  }
  float wsum = 0.f;
  for (int i = 0; i < np; ++i) { ls[i] = __expf(ls[i] - mx); wsum += ls[i]; }
  const float inv = 1.0f / wsum;
  float acc[8];
#pragma unroll
  for (int j = 0; j < 8; ++j) acc[j] = 0.f;
  for (int i = 0; i < np; ++i) {
    union { uint4 u; u16 h[8]; } X;
    X.u = *(const uint4*)(Opart + ((size_t)i * SEQL + row) * (size_t)HID + col);
#pragma unroll
    for (int j = 0; j < 8; ++j) acc[j] += ls[i] * bf2f(X.h[j]);
  }
  union { uint4 u; u16 h[8]; } O;
#pragma unroll
  for (int j = 0; j < 8; ++j) O.h[j] = f2bf(acc[j] * inv);
  *(uint4*)(amrg + (size_t)row * 2048 + col) = O.u;
}

extern "C" void kernel_launch(void* const* d_in, const int* in_sizes, int n_in,
                              void* d_out, int out_size, void* d_ws, size_t ws_size,
                              hipStream_t stream) {
  (void)in_sizes; (void)n_in; (void)out_size; (void)ws_size;
  const float* hidden = (const float*)d_in[0];
  const float* q_cos = (const float*)d_in[2];
  const float* q_sin = (const float*)d_in[3];
  const float* qc_cos = (const float*)d_in[4];
  const float* qc_sin = (const float*)d_in[5];
  const float* k_cos = (const float*)d_in[6];
  const float* k_sin = (const float*)d_in[7];
  const float* Wq = (const float*)d_in[8];
  const float* Wk = (const float*)d_in[9];
  const float* Wv = (const float*)d_in[10];
  const float* Wo = (const float*)d_in[11];
  float* out = (float*)d_out;

  char* ws = (char*)d_ws;
  // fixed region
  u16* Wo_bf = (u16*)(ws + 0);                      //  8,388,608
  u16* qa    = (u16*)(ws + 8388608);                // 20,447,232
  u16* qb    = (u16*)(ws + 28835840);               // 13,631,488
  u16* qf    = (u16*)(ws + 42467328);               //  6,815,744
  u16* k_bf  = (u16*)(ws + 49283072);               //  5,111,808
  u16* vT    = (u16*)(ws + 54394880);               //  5,111,808
  char* BIG  = ws + 59506688;
  // BIG overlay, phase 1-3
  u16* h_bf  = (u16*)(BIG + 0);                     // 20,447,232
  u16* Wqkv  = (u16*)(BIG + 20447232);              // 12,582,912
  u16* q_tmp = (u16*)(BIG + 33030144);              // 20,447,232
  u16* k_tmp = (u16*)(BIG + 53477376);              //  5,111,808
  // BIG overlay, phase 4-5
  u16* Opart = (u16*)(BIG + 0);                     // 61,341,696 (3 slots)
  float* lse = (float*)(BIG + 61341696);            //    958,464
  u16* amrg  = qa;                                  // alias: qa dead after attn

  cvt_all_kernel<<<dim3(20224), dim3(256), 0, stream>>>(hidden, Wq, Wk, Wv, Wo, h_bf, Wqkv, Wo_bf);
  gemm_qkv<<<dim3(936), 256, 0, stream>>>(h_bf, Wqkv, q_tmp, k_tmp, vT);
  rope_all_kernel<<<dim3(11232), dim3(256), 0, stream>>>(q_tmp, k_tmp, qa, qb, qf, k_bf,
                                                         q_cos, q_sin, qc_cos, qc_sin, k_cos, k_sin);
  attn_kernel<<<dim3(672), dim3(512), 0, stream>>>(qa, qb, qf, k_bf, vT, Opart, lse);
  merge_kernel<<<dim3(SEQL), dim3(256), 0, stream>>>(Opart, lse, amrg);
  gemm_o<<<dim3(624), 256, 0, stream>>>(amrg, Wo_bf, out);
}

// Round 17
// 564.151 us; speedup vs baseline: 1.5511x; 1.5511x over previous
//
#include <hip/hip_runtime.h>

typedef unsigned short u16;
typedef unsigned int u32;
typedef __attribute__((ext_vector_type(8))) __bf16 bf16x8;
typedef __attribute__((ext_vector_type(4))) float f32x4;
typedef __attribute__((ext_vector_type(16))) float f32x16;

#define CLEN 1664
#define SEQL 4992
#define NHEADS 16
#define HD 128
#define HID 2048
#define KVD 512
#define SCALE 0.08838834764831845f
#define SCLOG2E 0.12752615142058843f  // SCALE * log2(e)

__device__ __forceinline__ u16 f2bf(float f) {
  union { float f; u32 u; } v; v.f = f;
  u32 u = v.u;
  return (u16)((u + 0x7FFFu + ((u >> 16) & 1u)) >> 16);
}
__device__ __forceinline__ float bf2f(u16 h) {
  union { u32 u; float f; } v; v.u = (u32)h << 16;
  return v.f;
}
__device__ __forceinline__ f32x4 mfma16(bf16x8 a, bf16x8 b, f32x4 c) {
  return __builtin_amdgcn_mfma_f32_16x16x32_bf16(a, b, c, 0, 0, 0);
}
__device__ __forceinline__ f32x16 mfma32(bf16x8 a, bf16x8 b, f32x16 c) {
  return __builtin_amdgcn_mfma_f32_32x32x16_bf16(a, b, c, 0, 0, 0);
}
__device__ __forceinline__ u32 cvtpk(float lo, float hi) {
  u32 r;
  asm("v_cvt_pk_bf16_f32 %0, %1, %2" : "=v"(r) : "v"(lo), "v"(hi));
  return r;
}
__device__ __forceinline__ float exp2v(float x) {
  float r;
  asm("v_exp_f32 %0, %1" : "=v"(r) : "v"(x));
  return r;
}
__device__ __forceinline__ void gload_lds16(const u16* g, u16* l) {
  __builtin_amdgcn_global_load_lds((const __attribute__((address_space(1))) void*)g,
                                   (__attribute__((address_space(3))) void*)l, 16, 0, 0);
}

// ---------------- fused f32 -> bf16 convert (5 regions, 1 launch) ----------
#define CVT_Q0 2555904   // hidden  (10223616/4)
#define CVT_Q1 1048576   // Wq
#define CVT_Q2 262144    // Wk
#define CVT_Q3 262144    // Wv
#define CVT_Q4 1048576   // Wo
__device__ __forceinline__ void cvt4(const float* s, u16* d, int q) {
  float4 v = *(const float4*)(s + (size_t)q * 4);
  uint2 p;
  p.x = (u32)f2bf(v.x) | ((u32)f2bf(v.y) << 16);
  p.y = (u32)f2bf(v.z) | ((u32)f2bf(v.w) << 16);
  *(uint2*)(d + (size_t)q * 4) = p;
}
__global__ void cvt_all_kernel(const float* __restrict__ hidden, const float* __restrict__ Wq,
                               const float* __restrict__ Wk, const float* __restrict__ Wv,
                               const float* __restrict__ Wo, u16* __restrict__ h_bf,
                               u16* __restrict__ Wqkv, u16* __restrict__ Wo_bf) {
  int q = blockIdx.x * blockDim.x + threadIdx.x;
  if (q < CVT_Q0) { cvt4(hidden, h_bf, q); return; }
  q -= CVT_Q0;
  if (q < CVT_Q1) { cvt4(Wq, Wqkv, q); return; }
  q -= CVT_Q1;
  if (q < CVT_Q2) { cvt4(Wk, Wqkv + 2048 * 2048, q); return; }
  q -= CVT_Q2;
  if (q < CVT_Q3) { cvt4(Wv, Wqkv + 2560 * 2048, q); return; }
  q -= CVT_Q3;
  if (q < CVT_Q4) cvt4(Wo, Wo_bf, q);
}

// ---------------- fused RoPE (4 regions, 1 launch); Q paths pre-scaled -----
#define RP_N0 1277952  // qa : 4992*256
#define RP_N1 851968   // qb : 3328*256
#define RP_N2 425984   // qf : 1664*256
#define RP_N3 319488   // k  : 4992*64
__device__ __forceinline__ void rope8(const u16* __restrict__ src, u16* __restrict__ dst,
                                      const float* __restrict__ ctab, const float* __restrict__ stab,
                                      int s, int dstrow, int col, int rowlen, int pid, float scl) {
  const int dh = col & 127;
  const bool hih = dh >= 64;
  const u16* rowp = src + (size_t)s * rowlen;
  union { uint4 u; u16 h[8]; } X, P, O;
  X.u = *(const uint4*)(rowp + col);
  P.u = *(const uint4*)(rowp + col + (hih ? -64 : 64));
  const float* cp = ctab + pid * 128 + dh;
  const float* sp = stab + pid * 128 + dh;
#pragma unroll
  for (int j = 0; j < 8; ++j) {
    float v = bf2f(X.h[j]) * cp[j] + (hih ? bf2f(P.h[j]) : -bf2f(P.h[j])) * sp[j];
    O.h[j] = f2bf(v * scl);
  }
  *(uint4*)(dst + (size_t)dstrow * rowlen + col) = O.u;
}
__global__ void rope_all_kernel(const u16* __restrict__ q_tmp, const u16* __restrict__ k_tmp,
                                u16* __restrict__ qa, u16* __restrict__ qb, u16* __restrict__ qf,
                                u16* __restrict__ k_bf, const float* __restrict__ q_cos,
                                const float* __restrict__ q_sin, const float* __restrict__ qc_cos,
                                const float* __restrict__ qc_sin, const float* __restrict__ k_cos,
                                const float* __restrict__ k_sin) {
  int o = blockIdx.x * blockDim.x + threadIdx.x;
  if (o < RP_N0) {
    int r = o >> 8, col = (o & 255) * 8;
    rope8(q_tmp, qa, q_cos, q_sin, r, r, col, 2048, r % CLEN, SCLOG2E);
    return;
  }
  o -= RP_N0;
  if (o < RP_N1) {
    int r = o >> 8, col = (o & 255) * 8, s = CLEN + r;
    rope8(q_tmp, qb, qc_cos, qc_sin, s, r, col, 2048, s % CLEN, SCLOG2E);
    return;
  }
  o -= RP_N1;
  if (o < RP_N2) {
    int r = o >> 8, col = (o & 255) * 8, s = 2 * CLEN + r;
    rope8(q_tmp, qf, qc_cos, qc_sin, s, r, col, 2048, CLEN - 1, SCLOG2E);
    return;
  }
  o -= RP_N2;
  if (o < RP_N3) {
    int r = o >> 6, col = (o & 63) * 8;
    rope8(k_tmp, k_bf, k_cos, k_sin, r, r, col, 512, r, 1.0f);
  }
}

// ---------------- fused QKV GEMM (1D grid, XCD-swizzled) -------------------
__global__ __launch_bounds__(256) void gemm_qkv(const u16* __restrict__ A, const u16* __restrict__ B,
                                                u16* __restrict__ q_tmp, u16* __restrict__ k_tmp,
                                                u16* __restrict__ vT) {
  __shared__ __align__(16) u16 Al[128 * 64];
  __shared__ __align__(16) u16 Bl[128 * 64];
  const int K = HID;
  const int t = threadIdx.x;
  const int lane = t & 63, wid = t >> 6;
  const int g = lane >> 4, c = lane & 15;
  const int wr = wid >> 1, wc = wid & 1;
  const int bid = blockIdx.x;                      // 936 = 39 x 24, 936%8==0
  const int wg = (bid & 7) * 117 + (bid >> 3);     // XCD-contiguous chunks
  const int m0 = (wg % 39) * 128, n0 = (wg / 39) * 128;

  f32x4 acc[4][4];
#pragma unroll
  for (int m = 0; m < 4; ++m)
#pragma unroll
    for (int n = 0; n < 4; ++n) acc[m][n] = (f32x4){0.f, 0.f, 0.f, 0.f};

  const int scol = (t & 7) * 8;
  for (int k0 = 0; k0 < K; k0 += 64) {
    __syncthreads();
#pragma unroll
    for (int i = 0; i < 4; ++i) {
      const int r = i * 32 + (t >> 3);
      gload_lds16(A + (size_t)(m0 + r) * K + k0 + scol, Al + i * 2048 + wid * 512);
      gload_lds16(B + (size_t)(n0 + r) * K + k0 + scol, Bl + i * 2048 + wid * 512);
    }
    __syncthreads();
#pragma unroll
    for (int kk = 0; kk < 2; ++kk) {
      bf16x8 af[4], bfr[4];
#pragma unroll
      for (int m = 0; m < 4; ++m)
        af[m] = *(const bf16x8*)(Al + (wr * 64 + m * 16 + c) * 64 + kk * 32 + g * 8);
#pragma unroll
      for (int n = 0; n < 4; ++n)
        bfr[n] = *(const bf16x8*)(Bl + (wc * 64 + n * 16 + c) * 64 + kk * 32 + g * 8);
#pragma unroll
      for (int m = 0; m < 4; ++m)
#pragma unroll
        for (int n = 0; n < 4; ++n)
          acc[m][n] = mfma16(af[m], bfr[n], acc[m][n]);
    }
  }
#pragma unroll
  for (int m = 0; m < 4; ++m)
#pragma unroll
    for (int n = 0; n < 4; ++n)
#pragma unroll
      for (int j = 0; j < 4; ++j) {
        const int row = m0 + wr * 64 + m * 16 + 4 * g + j;
        const int col = n0 + wc * 64 + n * 16 + c;
        const float v = acc[m][n][j];
        if (n0 < 2048)       q_tmp[(size_t)row * 2048 + col] = f2bf(v);
        else if (n0 < 2560)  k_tmp[(size_t)row * 512 + (col - 2048)] = f2bf(v);
        else                 vT[(size_t)(col - 2560) * SEQL + row] = f2bf(v);
      }
}

// ---------------- O-projection GEMM (1D grid, XCD-swizzled), f32 out -------
__global__ __launch_bounds__(256) void gemm_o(const u16* __restrict__ A, const u16* __restrict__ B,
                                              float* __restrict__ Cf) {
  __shared__ __align__(16) u16 Al[128 * 64];
  __shared__ __align__(16) u16 Bl[128 * 64];
  const int K = HID, N = HID;
  const int t = threadIdx.x;
  const int lane = t & 63, wid = t >> 6;
  const int g = lane >> 4, c = lane & 15;
  const int wr = wid >> 1, wc = wid & 1;
  const int bid = blockIdx.x;                      // 624 = 39 x 16, 624%8==0
  const int wg = (bid & 7) * 78 + (bid >> 3);
  const int m0 = (wg % 39) * 128, n0 = (wg / 39) * 128;

  f32x4 acc[4][4];
#pragma unroll
  for (int m = 0; m < 4; ++m)
#pragma unroll
    for (int n = 0; n < 4; ++n) acc[m][n] = (f32x4){0.f, 0.f, 0.f, 0.f};

  const int scol = (t & 7) * 8;
  for (int k0 = 0; k0 < K; k0 += 64) {
    __syncthreads();
#pragma unroll
    for (int i = 0; i < 4; ++i) {
      const int r = i * 32 + (t >> 3);
      gload_lds16(A + (size_t)(m0 + r) * K + k0 + scol, Al + i * 2048 + wid * 512);
      gload_lds16(B + (size_t)(n0 + r) * K + k0 + scol, Bl + i * 2048 + wid * 512);
    }
    __syncthreads();
#pragma unroll
    for (int kk = 0; kk < 2; ++kk) {
      bf16x8 af[4], bfr[4];
#pragma unroll
      for (int m = 0; m < 4; ++m)
        af[m] = *(const bf16x8*)(Al + (wr * 64 + m * 16 + c) * 64 + kk * 32 + g * 8);
#pragma unroll
      for (int n = 0; n < 4; ++n)
        bfr[n] = *(const bf16x8*)(Bl + (wc * 64 + n * 16 + c) * 64 + kk * 32 + g * 8);
#pragma unroll
      for (int m = 0; m < 4; ++m)
#pragma unroll
        for (int n = 0; n < 4; ++n)
          acc[m][n] = mfma16(af[m], bfr[n], acc[m][n]);
    }
  }
#pragma unroll
  for (int m = 0; m < 4; ++m)
#pragma unroll
    for (int n = 0; n < 4; ++n)
#pragma unroll
      for (int j = 0; j < 4; ++j) {
        const int row = m0 + wr * 64 + m * 16 + 4 * g + j;
        const int col = n0 + wc * 64 + n * 16 + c;
        Cf[(size_t)row * N + col] = acc[m][n][j];
      }
}

// ---------------- deep-pipelined partial-attention kernel -------------------
// grid 672, 512 threads, r14 stream-to-XCD static placement. kv-tile = 32.
// 5 LDS buffers (80KB), stage-ahead 3, ONE barrier per tile, vmcnt(6) steady
// state -> loads stay in flight across barriers (T3/T4). Mask only on the
// single diagonal tile per wave (uniform branch).
__global__ __launch_bounds__(512, 4) void attn_kernel(
    const u16* __restrict__ qa, const u16* __restrict__ qbuf, const u16* __restrict__ qf,
    const u16* __restrict__ kbf, const u16* __restrict__ vT,
    u16* __restrict__ Opart, float* __restrict__ lseout) {
  __shared__ __align__(16) u16 smem[5 * 8192];  // 5 bufs x [K 4096 | V 4096] u16

  const int t = threadIdx.x, wid = t >> 6, lane = t & 63;
  const int ql = lane & 31, hi = lane >> 5;
  const int ksr = t >> 4, ksc = t & 15;  // K staging: row 0..31, 16B granule
  const int vsr = t >> 2, vsc = t & 3;   // V staging: row 0..127, 16B granule

  // ---- stream-affine static part decode (r14, proven) ----
  const int b = blockIdx.x;
  const int x = b & 7;                   // XCD (assumed b%8 round-robin)
  const int j = b >> 3;                  // 0..83 within this XCD
  const int k = x >> 1;                  // kv head group owned by this XCD pair
  int chunk, seg, qb, head_lo;
  if ((x & 1) == 0) {                    // stream (k, seg0)
    if (j < 56) {                        // fulls (1,0),(2,0)
      chunk = (j < 28) ? 1 : 2; seg = 0;
      const int jj = j % 28;
      qb = jj >> 2; head_lo = jj & 3;
    } else {                             // causal chunk0 (reads seg0), qb desc
      const int jj = j - 56;
      chunk = 0; seg = 0;
      qb = 6 - (jj >> 2); head_lo = jj & 3;
    }
  } else {                               // streams (k,seg1) then (k,seg2)
    if (j < 28) {                        // full (2,1)
      chunk = 2; seg = 1;
      qb = j >> 2; head_lo = j & 3;
    } else if (j < 56) {                 // causal chunk1 (reads seg1), qb desc
      const int jj = j - 28;
      chunk = 1; seg = 1;
      qb = 6 - (jj >> 2); head_lo = jj & 3;
    } else {                             // causal chunk2 (reads seg2), qb desc
      const int jj = j - 56;
      chunk = 2; seg = 2;
      qb = 6 - (jj >> 2); head_lo = jj & 3;
    }
  }
  const int head = k * 4 + head_lo;
  const bool causal = (seg == chunk);
  const int nt = causal ? ((qb == 6) ? 52 : (8 * qb + 8)) : 52;  // 32-kv tiles
  const int slot = causal ? 0 : ((chunk - seg == 1) ? 1 : 2);
  const int kvh = k;
  const int kvbase = seg * CLEN;
  const int qcb = qb * 256 + wid * 32;
  const int qpos = qcb + ql;
  const bool wact = qcb < CLEN;          // qb==6 upper waves idle

  const u16* qp; int qoff;
  if (causal)                { qp = qa;   qoff = 0; }
  else if (chunk - seg == 1) { qp = qbuf; qoff = CLEN; }
  else                       { qp = qf;   qoff = 2 * CLEN; }

  bf16x8 aq[8];
  {
    const int qrow = wact ? (chunk * CLEN + qpos - qoff) : 0;
    const u16* qptr = qp + (size_t)qrow * HID + head * HD + hi * 8;
#pragma unroll
    for (int ck = 0; ck < 8; ++ck) aq[ck] = *(const bf16x8*)(qptr + ck * 16);
  }

  float l_r = 0.f;
  f32x16 oacc[4];
#pragma unroll
  for (int db = 0; db < 4; ++db)
#pragma unroll
    for (int r = 0; r < 16; ++r) oacc[db][r] = 0.f;

  const u16* ksrc = kbf + (size_t)kvbase * KVD + kvh * HD + ((ksc ^ (ksr & 7)) * 8)
                    + (size_t)ksr * KVD;
  const u16* vsrc = vT + (size_t)(kvh * HD + vsr) * SEQL + kvbase + ((vsc ^ (vsr & 3)) * 8);

  auto stage = [&](int p, int kt) {
    const int kv0 = kt * 32;
    gload_lds16(ksrc + (size_t)kv0 * KVD, smem + p * 8192 + wid * 512);
    gload_lds16(vsrc + kv0, smem + p * 8192 + 4096 + wid * 512);
  };

  stage(0, 0);
  stage(1, 1);
  stage(2, 2);
  for (int kt = 0; kt < nt; ++kt) {
    if (kt + 3 < nt) stage((kt + 3) % 5, kt + 3);
    const int rem = nt - 1 - kt;
    if (rem >= 3)      asm volatile("s_waitcnt vmcnt(6)" ::: "memory");
    else if (rem == 2) asm volatile("s_waitcnt vmcnt(4)" ::: "memory");
    else if (rem == 1) asm volatile("s_waitcnt vmcnt(2)" ::: "memory");
    else               asm volatile("s_waitcnt vmcnt(0)" ::: "memory");
    __builtin_amdgcn_s_barrier();
    const int kv0 = kt * 32;
    if (wact && !(causal && kv0 > qcb)) {
      const u16* Kb = smem + (kt % 5) * 8192;
      const u16* Vb = Kb + 4096;
      // ---- QK^T (swapped): lane owns q=ql, 16 kv rows ----
      f32x16 sacc;
#pragma unroll
      for (int r = 0; r < 16; ++r) sacc[r] = 0.f;
      const int q7 = ql & 7;
      __builtin_amdgcn_s_setprio(1);
#pragma unroll
      for (int ck = 0; ck < 8; ++ck) {
        bf16x8 kb = *(const bf16x8*)(Kb + ql * 128 + (((2 * ck + hi) ^ q7) * 8));
        sacc = mfma32(kb, aq[ck], sacc);
      }
      __builtin_amdgcn_s_setprio(0);
      // ---- softmax, fixed m=0; pre-scaled by SCALE*log2e -> 2^x ----
      float e[16];
      float rs = 0.f;
      if (causal && kv0 == qcb) {        // diagonal tile: mask (uniform branch)
        const int thr = ql - 4 * hi;
#pragma unroll
        for (int r = 0; r < 16; ++r) {
          const int crow_r = (r & 3) + 8 * (r >> 2);
          float ev = (crow_r > thr) ? -1e30f : sacc[r];
          e[r] = exp2v(ev);
          rs += e[r];
        }
      } else {
#pragma unroll
        for (int r = 0; r < 16; ++r) { e[r] = exp2v(sacc[r]); rs += e[r]; }
      }
      rs += __shfl_xor(rs, 32);
      l_r += rs;
      u32 wp[8];
#pragma unroll
      for (int j2 = 0; j2 < 8; ++j2) wp[j2] = cvtpk(e[2 * j2], e[2 * j2 + 1]);
      // ---- PV ----
      __builtin_amdgcn_s_setprio(1);
#pragma unroll
      for (int ks = 0; ks < 2; ++ks) {
        union { uint4 u; bf16x8 v; } pa;
        pa.u.x = wp[4 * ks]; pa.u.y = wp[4 * ks + 1];
        pa.u.z = wp[4 * ks + 2]; pa.u.w = wp[4 * ks + 3];
        const int g8 = 4 * ks + hi;            // b64 granule, 0..7
#pragma unroll
        for (int db = 0; db < 4; ++db) {
          const int vrow = 32 * db + ql;
          const int sw3 = vrow & 3;
          const uint2 v0 = *(const uint2*)(Vb + vrow * 32 + (((g8 >> 1) ^ sw3) * 8) + (g8 & 1) * 4);
          const uint2 v1 = *(const uint2*)(Vb + vrow * 32 + ((((g8 + 2) >> 1) ^ sw3) * 8) + (g8 & 1) * 4);
          union { uint4 u; bf16x8 v; } bv;
          bv.u.x = v0.x; bv.u.y = v0.y; bv.u.z = v1.x; bv.u.w = v1.y;
          oacc[db] = mfma32(pa.v, bv.v, oacc[db]);
        }
      }
      __builtin_amdgcn_s_setprio(0);
    }
  }
  __syncthreads();  // buffers become epilogue scratch
  // ---- epilogue: scale, transpose via LDS, 256B rows ----
  if (wact) {
    const float linv = 1.0f / l_r;
    u16* scr = smem + wid * 4096;  // per-wave 32x128 u16 scratch (8KB/wave)
#pragma unroll
    for (int r = 0; r < 16; ++r) {
      const int rrow = (r & 3) + 8 * (r >> 2) + 4 * hi;
      const float li = __shfl(linv, rrow);
#pragma unroll
      for (int db = 0; db < 4; ++db)
        scr[rrow * 128 + db * 32 + ql] = f2bf(oacc[db][r] * li);
    }
    asm volatile("s_waitcnt lgkmcnt(0)" ::: "memory");
    const int rcol = lane & 15;
#pragma unroll
    for (int p = 0; p < 8; ++p) {
      const int row = p * 4 + (lane >> 4);
      uint4 v = *(const uint4*)(scr + row * 128 + rcol * 8);
      const size_t grow = (size_t)(chunk * CLEN + qcb + row);
      *(uint4*)(Opart + ((size_t)slot * SEQL + grow) * HID + head * HD + rcol * 8) = v;
    }
    if (hi == 0)
      lseout[((size_t)slot * NHEADS + head) * SEQL + chunk * CLEN + qcb + ql] = __logf(l_r);
  }
}

// ---------------- merge partials (softmax over lse) ------------------------
__global__ void merge_kernel(const u16* __restrict__ Opart, const float* __restrict__ lse,
                             u16* __restrict__ amrg) {
  const int idx = blockIdx.x * blockDim.x + threadIdx.x;  // 4992*256 threads
  const int row = idx >> 8;
  const int col = (idx & 255) * 8;
  const int head = col >> 7;
  const int np = row / CLEN + 1;
  float ls[3];
  float mx = -1e30f;
  for (int i = 0; i < np; ++i) {
    ls[i] = lse[((size_t)i * NHEADS + head) * SEQL + row];
    mx = fmaxf(mx, ls[i]);
  }
  float wsum = 0.f;
  for (int i = 0; i < np; ++i) { ls[i] = __expf(ls[i] - mx); wsum += ls[i]; }
  const float inv = 1.0f / wsum;
  float acc[8];
#pragma unroll
  for (int j = 0; j < 8; ++j) acc[j] = 0.f;
  for (int i = 0; i < np; ++i) {
    union { uint4 u; u16 h[8]; } X;
    X.u = *(const uint4*)(Opart + ((size_t)i * SEQL + row) * (size_t)HID + col);
#pragma unroll
    for (int j = 0; j < 8; ++j) acc[j] += ls[i] * bf2f(X.h[j]);
  }
  union { uint4 u; u16 h[8]; } O;
#pragma unroll
  for (int j = 0; j < 8; ++j) O.h[j] = f2bf(acc[j] * inv);
  *(uint4*)(amrg + (size_t)row * 2048 + col) = O.u;
}

extern "C" void kernel_launch(void* const* d_in, const int* in_sizes, int n_in,
                              void* d_out, int out_size, void* d_ws, size_t ws_size,
                              hipStream_t stream) {
  (void)in_sizes; (void)n_in; (void)out_size; (void)ws_size;
  const float* hidden = (const float*)d_in[0];
  const float* q_cos = (const float*)d_in[2];
  const float* q_sin = (const float*)d_in[3];
  const float* qc_cos = (const float*)d_in[4];
  const float* qc_sin = (const float*)d_in[5];
  const float* k_cos = (const float*)d_in[6];
  const float* k_sin = (const float*)d_in[7];
  const float* Wq = (const float*)d_in[8];
  const float* Wk = (const float*)d_in[9];
  const float* Wv = (const float*)d_in[10];
  const float* Wo = (const float*)d_in[11];
  float* out = (float*)d_out;

  char* ws = (char*)d_ws;
  // fixed region
  u16* Wo_bf = (u16*)(ws + 0);                      //  8,388,608
  u16* qa    = (u16*)(ws + 8388608);                // 20,447,232
  u16* qb    = (u16*)(ws + 28835840);               // 13,631,488
  u16* qf    = (u16*)(ws + 42467328);               //  6,815,744
  u16* k_bf  = (u16*)(ws + 49283072);               //  5,111,808
  u16* vT    = (u16*)(ws + 54394880);               //  5,111,808
  char* BIG  = ws + 59506688;
  // BIG overlay, phase 1-3
  u16* h_bf  = (u16*)(BIG + 0);                     // 20,447,232
  u16* Wqkv  = (u16*)(BIG + 20447232);              // 12,582,912
  u16* q_tmp = (u16*)(BIG + 33030144);              // 20,447,232
  u16* k_tmp = (u16*)(BIG + 53477376);              //  5,111,808
  // BIG overlay, phase 4-5
  u16* Opart = (u16*)(BIG + 0);                     // 61,341,696 (3 slots)
  float* lse = (float*)(BIG + 61341696);            //    958,464
  u16* amrg  = qa;                                  // alias: qa dead after attn

  cvt_all_kernel<<<dim3(20224), dim3(256), 0, stream>>>(hidden, Wq, Wk, Wv, Wo, h_bf, Wqkv, Wo_bf);
  gemm_qkv<<<dim3(936), 256, 0, stream>>>(h_bf, Wqkv, q_tmp, k_tmp, vT);
  rope_all_kernel<<<dim3(11232), dim3(256), 0, stream>>>(q_tmp, k_tmp, qa, qb, qf, k_bf,
                                                         q_cos, q_sin, qc_cos, qc_sin, k_cos, k_sin);
  attn_kernel<<<dim3(672), dim3(512), 0, stream>>>(qa, qb, qf, k_bf, vT, Opart, lse);
  merge_kernel<<<dim3(SEQL), dim3(256), 0, stream>>>(Opart, lse, amrg);
  gemm_o<<<dim3(624), 256, 0, stream>>>(amrg, Wo_bf, out);
}

// Round 18
// 517.791 us; speedup vs baseline: 1.6899x; 1.0895x over previous
//
#include <hip/hip_runtime.h>

typedef unsigned short u16;
typedef unsigned int u32;
typedef __attribute__((ext_vector_type(8))) __bf16 bf16x8;
typedef __attribute__((ext_vector_type(4))) float f32x4;
typedef __attribute__((ext_vector_type(16))) float f32x16;

#define CLEN 1664
#define SEQL 4992
#define NHEADS 16
#define HD 128
#define HID 2048
#define KVD 512
#define SCALE 0.08838834764831845f
#define SCLOG2E 0.12752615142058843f  // SCALE * log2(e)

__device__ __forceinline__ u16 f2bf(float f) {
  union { float f; u32 u; } v; v.f = f;
  u32 u = v.u;
  return (u16)((u + 0x7FFFu + ((u >> 16) & 1u)) >> 16);
}
__device__ __forceinline__ float bf2f(u16 h) {
  union { u32 u; float f; } v; v.u = (u32)h << 16;
  return v.f;
}
__device__ __forceinline__ f32x4 mfma16(bf16x8 a, bf16x8 b, f32x4 c) {
  return __builtin_amdgcn_mfma_f32_16x16x32_bf16(a, b, c, 0, 0, 0);
}
__device__ __forceinline__ f32x16 mfma32(bf16x8 a, bf16x8 b, f32x16 c) {
  return __builtin_amdgcn_mfma_f32_32x32x16_bf16(a, b, c, 0, 0, 0);
}
__device__ __forceinline__ u32 cvtpk(float lo, float hi) {
  u32 r;
  asm("v_cvt_pk_bf16_f32 %0, %1, %2" : "=v"(r) : "v"(lo), "v"(hi));
  return r;
}
__device__ __forceinline__ float exp2v(float x) {
  float r;
  asm("v_exp_f32 %0, %1" : "=v"(r) : "v"(x));
  return r;
}
__device__ __forceinline__ void gload_lds16(const u16* g, u16* l) {
  __builtin_amdgcn_global_load_lds((const __attribute__((address_space(1))) void*)g,
                                   (__attribute__((address_space(3))) void*)l, 16, 0, 0);
}

// ---------------- fused f32 -> bf16 convert (5 regions, 1 launch) ----------
#define CVT_Q0 2555904   // hidden  (10223616/4)
#define CVT_Q1 1048576   // Wq
#define CVT_Q2 262144    // Wk
#define CVT_Q3 262144    // Wv
#define CVT_Q4 1048576   // Wo
__device__ __forceinline__ void cvt4(const float* s, u16* d, int q) {
  float4 v = *(const float4*)(s + (size_t)q * 4);
  uint2 p;
  p.x = (u32)f2bf(v.x) | ((u32)f2bf(v.y) << 16);
  p.y = (u32)f2bf(v.z) | ((u32)f2bf(v.w) << 16);
  *(uint2*)(d + (size_t)q * 4) = p;
}
__global__ void cvt_all_kernel(const float* __restrict__ hidden, const float* __restrict__ Wq,
                               const float* __restrict__ Wk, const float* __restrict__ Wv,
                               const float* __restrict__ Wo, u16* __restrict__ h_bf,
                               u16* __restrict__ Wqkv, u16* __restrict__ Wo_bf) {
  int q = blockIdx.x * blockDim.x + threadIdx.x;
  if (q < CVT_Q0) { cvt4(hidden, h_bf, q); return; }
  q -= CVT_Q0;
  if (q < CVT_Q1) { cvt4(Wq, Wqkv, q); return; }
  q -= CVT_Q1;
  if (q < CVT_Q2) { cvt4(Wk, Wqkv + 2048 * 2048, q); return; }
  q -= CVT_Q2;
  if (q < CVT_Q3) { cvt4(Wv, Wqkv + 2560 * 2048, q); return; }
  q -= CVT_Q3;
  if (q < CVT_Q4) cvt4(Wo, Wo_bf, q);
}

// ---------------- fused RoPE (4 regions, 1 launch); Q paths pre-scaled -----
#define RP_N0 1277952  // qa : 4992*256
#define RP_N1 851968   // qb : 3328*256
#define RP_N2 425984   // qf : 1664*256
#define RP_N3 319488   // k  : 4992*64
__device__ __forceinline__ void rope8(const u16* __restrict__ src, u16* __restrict__ dst,
                                      const float* __restrict__ ctab, const float* __restrict__ stab,
                                      int s, int dstrow, int col, int rowlen, int pid, float scl) {
  const int dh = col & 127;
  const bool hih = dh >= 64;
  const u16* rowp = src + (size_t)s * rowlen;
  union { uint4 u; u16 h[8]; } X, P, O;
  X.u = *(const uint4*)(rowp + col);
  P.u = *(const uint4*)(rowp + col + (hih ? -64 : 64));
  const float* cp = ctab + pid * 128 + dh;
  const float* sp = stab + pid * 128 + dh;
#pragma unroll
  for (int j = 0; j < 8; ++j) {
    float v = bf2f(X.h[j]) * cp[j] + (hih ? bf2f(P.h[j]) : -bf2f(P.h[j])) * sp[j];
    O.h[j] = f2bf(v * scl);
  }
  *(uint4*)(dst + (size_t)dstrow * rowlen + col) = O.u;
}
__global__ void rope_all_kernel(const u16* __restrict__ q_tmp, const u16* __restrict__ k_tmp,
                                u16* __restrict__ qa, u16* __restrict__ qb, u16* __restrict__ qf,
                                u16* __restrict__ k_bf, const float* __restrict__ q_cos,
                                const float* __restrict__ q_sin, const float* __restrict__ qc_cos,
                                const float* __restrict__ qc_sin, const float* __restrict__ k_cos,
                                const float* __restrict__ k_sin) {
  int o = blockIdx.x * blockDim.x + threadIdx.x;
  if (o < RP_N0) {
    int r = o >> 8, col = (o & 255) * 8;
    rope8(q_tmp, qa, q_cos, q_sin, r, r, col, 2048, r % CLEN, SCLOG2E);
    return;
  }
  o -= RP_N0;
  if (o < RP_N1) {
    int r = o >> 8, col = (o & 255) * 8, s = CLEN + r;
    rope8(q_tmp, qb, qc_cos, qc_sin, s, r, col, 2048, s % CLEN, SCLOG2E);
    return;
  }
  o -= RP_N1;
  if (o < RP_N2) {
    int r = o >> 8, col = (o & 255) * 8, s = 2 * CLEN + r;
    rope8(q_tmp, qf, qc_cos, qc_sin, s, r, col, 2048, CLEN - 1, SCLOG2E);
    return;
  }
  o -= RP_N2;
  if (o < RP_N3) {
    int r = o >> 6, col = (o & 63) * 8;
    rope8(k_tmp, k_bf, k_cos, k_sin, r, r, col, 512, r, 1.0f);
  }
}

// ---------------- fused QKV GEMM: 256x256 tile, counted-vmcnt pipeline -----
// 512 threads = 8 waves (2M x 4N). BK=64, double-buffered 128KB LDS.
// 4 phases per K-tile: each issues a prefetch pair for tile kt+1 and computes
// 16 MFMA; vmcnt(2) (never 0 mid-loop) + 2 barriers per K-tile.
__global__ __launch_bounds__(512) void gemm_qkv(const u16* __restrict__ A, const u16* __restrict__ B,
                                                u16* __restrict__ q_tmp, u16* __restrict__ k_tmp,
                                                u16* __restrict__ vT) {
  __shared__ __align__(16) u16 Al[2][256 * 64];
  __shared__ __align__(16) u16 Bl[2][256 * 64];
  const int K = HID;
  const int t = threadIdx.x;
  const int lane = t & 63, wid = t >> 6;
  const int g = lane >> 4, c = lane & 15;
  const int wm = wid >> 2, wn = wid & 3;
  const int bid = blockIdx.x;              // 240 = 20 x 12, 240%8==0
  const int wg = (bid & 7) * 30 + (bid >> 3);
  const int m0 = (wg % 20) * 256, n0 = (wg / 20) * 256;

  f32x4 acc[8][4];
#pragma unroll
  for (int mf = 0; mf < 8; ++mf)
#pragma unroll
    for (int nf = 0; nf < 4; ++nf) acc[mf][nf] = (f32x4){0.f, 0.f, 0.f, 0.f};

  const int srow = t >> 3;        // 0..63
  const int scol = (t & 7) * 8;   // 0..56

  auto stgA = [&](int buf, int kt, int i) {
    gload_lds16(A + (size_t)(m0 + i * 64 + srow) * K + kt * 64 + scol,
                &Al[buf][i * 4096 + wid * 512]);
  };
  auto stgB = [&](int buf, int kt, int i) {
    gload_lds16(B + (size_t)(n0 + i * 64 + srow) * K + kt * 64 + scol,
                &Bl[buf][i * 4096 + wid * 512]);
  };

#pragma unroll
  for (int i = 0; i < 4; ++i) { stgA(0, 0, i); stgB(0, 0, i); }

  const int NT = K / 64;  // 32
  for (int kt = 0; kt < NT; ++kt) {
    const int buf = kt & 1, nb = buf ^ 1;
    const bool nx = (kt + 1 < NT);
#pragma unroll
    for (int ph = 0; ph < 4; ++ph) {
      if (nx) {
        if (ph < 2) { stgA(nb, kt + 1, 2 * ph); stgA(nb, kt + 1, 2 * ph + 1); }
        else        { stgB(nb, kt + 1, 2 * (ph - 2)); stgB(nb, kt + 1, 2 * (ph - 2) + 1); }
      }
      if (ph == 0) {
        if (nx) asm volatile("s_waitcnt vmcnt(2)" ::: "memory");
        else    asm volatile("s_waitcnt vmcnt(0)" ::: "memory");
        __builtin_amdgcn_s_barrier();
      }
      const int mfa = 2 * ph;
      bf16x8 af[2][2], bfr[4][2];
#pragma unroll
      for (int q2 = 0; q2 < 2; ++q2)
#pragma unroll
        for (int ks = 0; ks < 2; ++ks)
          af[q2][ks] = *(const bf16x8*)(&Al[buf][(wm * 128 + (mfa + q2) * 16 + c) * 64 + ks * 32 + g * 8]);
#pragma unroll
      for (int nf = 0; nf < 4; ++nf)
#pragma unroll
        for (int ks = 0; ks < 2; ++ks)
          bfr[nf][ks] = *(const bf16x8*)(&Bl[buf][(wn * 64 + nf * 16 + c) * 64 + ks * 32 + g * 8]);
      __builtin_amdgcn_s_setprio(1);
#pragma unroll
      for (int q2 = 0; q2 < 2; ++q2)
#pragma unroll
        for (int nf = 0; nf < 4; ++nf)
#pragma unroll
          for (int ks = 0; ks < 2; ++ks)
            acc[mfa + q2][nf] = mfma16(af[q2][ks], bfr[nf][ks], acc[mfa + q2][nf]);
      __builtin_amdgcn_s_setprio(0);
    }
    __builtin_amdgcn_s_barrier();
  }
  // epilogue: route q/k/vT, guard ragged M
#pragma unroll
  for (int mf = 0; mf < 8; ++mf)
#pragma unroll
    for (int nf = 0; nf < 4; ++nf)
#pragma unroll
      for (int j = 0; j < 4; ++j) {
        const int row = m0 + wm * 128 + mf * 16 + 4 * g + j;
        const int col = n0 + wn * 64 + nf * 16 + c;
        if (row < SEQL) {
          const float v = acc[mf][nf][j];
          if (col < 2048)       q_tmp[(size_t)row * 2048 + col] = f2bf(v);
          else if (col < 2560)  k_tmp[(size_t)row * 512 + (col - 2048)] = f2bf(v);
          else                  vT[(size_t)(col - 2560) * SEQL + row] = f2bf(v);
        }
      }
}

// ---------------- O-projection GEMM (1D grid, XCD-swizzled), f32 out -------
__global__ __launch_bounds__(256) void gemm_o(const u16* __restrict__ A, const u16* __restrict__ B,
                                              float* __restrict__ Cf) {
  __shared__ __align__(16) u16 Al[128 * 64];
  __shared__ __align__(16) u16 Bl[128 * 64];
  const int K = HID, N = HID;
  const int t = threadIdx.x;
  const int lane = t & 63, wid = t >> 6;
  const int g = lane >> 4, c = lane & 15;
  const int wr = wid >> 1, wc = wid & 1;
  const int bid = blockIdx.x;                      // 624 = 39 x 16, 624%8==0
  const int wg = (bid & 7) * 78 + (bid >> 3);
  const int m0 = (wg % 39) * 128, n0 = (wg / 39) * 128;

  f32x4 acc[4][4];
#pragma unroll
  for (int m = 0; m < 4; ++m)
#pragma unroll
    for (int n = 0; n < 4; ++n) acc[m][n] = (f32x4){0.f, 0.f, 0.f, 0.f};

  const int scol = (t & 7) * 8;
  for (int k0 = 0; k0 < K; k0 += 64) {
    __syncthreads();
#pragma unroll
    for (int i = 0; i < 4; ++i) {
      const int r = i * 32 + (t >> 3);
      gload_lds16(A + (size_t)(m0 + r) * K + k0 + scol, Al + i * 2048 + wid * 512);
      gload_lds16(B + (size_t)(n0 + r) * K + k0 + scol, Bl + i * 2048 + wid * 512);
    }
    __syncthreads();
#pragma unroll
    for (int kk = 0; kk < 2; ++kk) {
      bf16x8 af[4], bfr[4];
#pragma unroll
      for (int m = 0; m < 4; ++m)
        af[m] = *(const bf16x8*)(Al + (wr * 64 + m * 16 + c) * 64 + kk * 32 + g * 8);
#pragma unroll
      for (int n = 0; n < 4; ++n)
        bfr[n] = *(const bf16x8*)(Bl + (wc * 64 + n * 16 + c) * 64 + kk * 32 + g * 8);
#pragma unroll
      for (int m = 0; m < 4; ++m)
#pragma unroll
        for (int n = 0; n < 4; ++n)
          acc[m][n] = mfma16(af[m], bfr[n], acc[m][n]);
    }
  }
#pragma unroll
  for (int m = 0; m < 4; ++m)
#pragma unroll
    for (int n = 0; n < 4; ++n)
#pragma unroll
      for (int j = 0; j < 4; ++j) {
        const int row = m0 + wr * 64 + m * 16 + 4 * g + j;
        const int col = n0 + wc * 64 + n * 16 + c;
        Cf[(size_t)row * N + col] = acc[m][n][j];
      }
}

// ---------------- static-schedule partial-attention kernel (r12, proven) ----
__global__ __launch_bounds__(512, 4) void attn_kernel(
    const u16* __restrict__ qa, const u16* __restrict__ qbuf, const u16* __restrict__ qf,
    const u16* __restrict__ kbf, const u16* __restrict__ vT,
    u16* __restrict__ Opart, float* __restrict__ lseout) {
  __shared__ __align__(16) u16 smem[2 * 16384];  // [buf][K 8192 | V 8192] u16

  const int t = threadIdx.x, wid = t >> 6, lane = t & 63;
  const int ql = lane & 31, hi = lane >> 5;
  const int ksr = t >> 4, ksc = t & 15;  // K staging: row ksr+32i
  const int vsr = t >> 3, vsc = t & 7;   // V staging: row vsr+64i

  // ---- static part decode: fulls first (26 tiles), then causal qb6..qb0 ----
  const int b = blockIdx.x;
  int chunk, seg, qb, head;
  if (b < 336) {
    head = b & 15;
    const int f = b >> 4;          // 0..20
    const int part = f / 7; qb = f % 7;
    chunk = (part == 0) ? 1 : 2;
    seg = (part == 2) ? 1 : 0;
  } else {
    const int i = b - 336;         // 0..335
    qb = 6 - i / 48;               // 48 parts per qb band
    const int j = i % 48;
    head = j & 15; chunk = j >> 4; seg = chunk;
  }
  const bool causal = (seg == chunk);
  const int nt = causal ? ((qb == 6) ? 26 : (4 * qb + 4)) : 26;
  const int slot = causal ? 0 : ((chunk - seg == 1) ? 1 : 2);
  const int kvh = head >> 2;
  const int kvbase = seg * CLEN;
  const int qcb = qb * 256 + wid * 32;
  const int qpos = qcb + ql;
  const bool wact = qcb < CLEN;    // qb==6 upper waves idle

  const u16* qp; int qoff;
  if (causal)                { qp = qa;   qoff = 0; }
  else if (chunk - seg == 1) { qp = qbuf; qoff = CLEN; }
  else                       { qp = qf;   qoff = 2 * CLEN; }

  bf16x8 aq[8];
  {
    const int qrow = wact ? (chunk * CLEN + qpos - qoff) : 0;
    const u16* qptr = qp + (size_t)qrow * HID + head * HD + hi * 8;
#pragma unroll
    for (int ck = 0; ck < 8; ++ck) aq[ck] = *(const bf16x8*)(qptr + ck * 16);
  }

  float l_r = 0.f;
  f32x16 oacc[4];
#pragma unroll
  for (int db = 0; db < 4; ++db)
#pragma unroll
    for (int r = 0; r < 16; ++r) oacc[db][r] = 0.f;

  auto stage = [&](int bb, int kt) {
    const int kv0 = kt * 64;
#pragma unroll
    for (int i = 0; i < 2; ++i) {
      const int rr = ksr + 32 * i;
      const int gs = ksc ^ (rr & 7);
      gload_lds16(kbf + (size_t)(kvbase + kv0 + rr) * KVD + kvh * HD + gs * 8,
                  smem + bb * 16384 + i * 4096 + wid * 512);
    }
#pragma unroll
    for (int i = 0; i < 2; ++i) {
      const int rr = vsr + 64 * i;
      const int gs = vsc ^ (rr & 7);
      gload_lds16(vT + (size_t)(kvh * HD + rr) * SEQL + kvbase + kv0 + gs * 8,
                  smem + bb * 16384 + 8192 + i * 4096 + wid * 512);
    }
  };

  stage(0, 0);
  int cur = 0;
  for (int kt = 0; kt < nt; ++kt) {
    if (kt + 1 < nt) {
      stage(cur ^ 1, kt + 1);
      asm volatile("s_waitcnt vmcnt(4)" ::: "memory");
    } else {
      asm volatile("s_waitcnt vmcnt(0)" ::: "memory");
    }
    __builtin_amdgcn_s_barrier();
    const int kv0 = kt * 64;
    const u16* Kb = smem + cur * 16384;
    const u16* Vb = smem + cur * 16384 + 8192;
#pragma unroll
    for (int s = 0; s < 2; ++s) {
      if (wact && !(causal && kv0 + 32 * s > qcb + 31)) {
        f32x16 sacc;
#pragma unroll
        for (int r = 0; r < 16; ++r) sacc[r] = 0.f;
        const int kr = 32 * s + ql;
        const int r7 = lane & 7;
        __builtin_amdgcn_s_setprio(1);
#pragma unroll
        for (int ck = 0; ck < 8; ++ck) {
          bf16x8 kb = *(const bf16x8*)(Kb + kr * 128 + (((2 * ck + hi) ^ r7) * 8));
          sacc = mfma32(kb, aq[ck], sacc);
        }
        __builtin_amdgcn_s_setprio(0);
        const int thr = qpos - kv0 - 32 * s - 4 * hi;
        float e[16];
        float rs = 0.f;
#pragma unroll
        for (int r = 0; r < 16; ++r) {
          const int crow_r = (r & 3) + 8 * (r >> 2);
          float ev = (causal && crow_r > thr) ? -1e30f : sacc[r];
          e[r] = exp2v(ev);
          rs += e[r];
        }
        rs += __shfl_xor(rs, 32);
        l_r += rs;
        u32 wp[8];
#pragma unroll
        for (int j2 = 0; j2 < 8; ++j2) wp[j2] = cvtpk(e[2 * j2], e[2 * j2 + 1]);
        __builtin_amdgcn_s_setprio(1);
#pragma unroll
        for (int ks = 0; ks < 2; ++ks) {
          union { uint4 u; bf16x8 v; } pa;
          pa.u.x = wp[4 * ks]; pa.u.y = wp[4 * ks + 1];
          pa.u.z = wp[4 * ks + 2]; pa.u.w = wp[4 * ks + 3];
          const int g4a = 8 * s + 4 * ks + hi;
          const int sw = (lane & 7) << 1;
#pragma unroll
          for (int db = 0; db < 4; ++db) {
            const int vrow = 32 * db + ql;
            const uint2 v0 = *(const uint2*)(Vb + vrow * 64 + ((g4a ^ sw) * 4));
            const uint2 v1 = *(const uint2*)(Vb + vrow * 64 + (((g4a + 2) ^ sw) * 4));
            union { uint4 u; bf16x8 v; } bv;
            bv.u.x = v0.x; bv.u.y = v0.y; bv.u.z = v1.x; bv.u.w = v1.y;
            oacc[db] = mfma32(pa.v, bv.v, oacc[db]);
          }
        }
        __builtin_amdgcn_s_setprio(0);
      }
    }
    __builtin_amdgcn_s_barrier();
    cur ^= 1;
  }
  // ---- epilogue: scale, transpose via LDS (K/V bufs are dead), 256B rows ---
  if (wact) {
    const float linv = 1.0f / l_r;
    u16* scr = smem + wid * 4096;  // per-wave 32x128 u16 scratch
#pragma unroll
    for (int r = 0; r < 16; ++r) {
      const int rrow = (r & 3) + 8 * (r >> 2) + 4 * hi;
      const float li = __shfl(linv, rrow);
#pragma unroll
      for (int db = 0; db < 4; ++db)
        scr[rrow * 128 + db * 32 + ql] = f2bf(oacc[db][r] * li);
    }
    asm volatile("s_waitcnt lgkmcnt(0)" ::: "memory");
    const int rcol = lane & 15;
#pragma unroll
    for (int p = 0; p < 8; ++p) {
      const int row = p * 4 + (lane >> 4);
      uint4 v = *(const uint4*)(scr + row * 128 + rcol * 8);
      const size_t grow = (size_t)(chunk * CLEN + qcb + row);
      *(uint4*)(Opart + ((size_t)slot * SEQL + grow) * HID + head * HD + rcol * 8) = v;
    }
    if (hi == 0)
      lseout[((size_t)slot * NHEADS + head) * SEQL + chunk * CLEN + qcb + ql] = __logf(l_r);
  }
}

// ---------------- merge partials (softmax over lse) ------------------------
__global__ void merge_kernel(const u16* __restrict__ Opart, const float* __restrict__ lse,
                             u16* __restrict__ amrg) {
  const int idx = blockIdx.x * blockDim.x + threadIdx.x;  // 4992*256 threads
  const int row = idx >> 8;
  const int col = (idx & 255) * 8;
  const int head = col >> 7;
  const int np = row / CLEN + 1;
  float ls[3];
  float mx = -1e30f;
  for (int i = 0; i < np; ++i) {
    ls[i] = lse[((size_t)i * NHEADS + head) * SEQL + row];
    mx = fmaxf(mx, ls[i]);
  }
  float wsum = 0.f;
  for (int i = 0; i < np; ++i) { ls[i] = __expf(ls[i] - mx); wsum += ls[i]; }
  const float inv = 1.0f / wsum;
  float acc[8];
#pragma unroll
  for (int j = 0; j < 8; ++j) acc[j] = 0.f;
  for (int i = 0; i < np; ++i) {
    union { uint4 u; u16 h[8]; } X;
    X.u = *(const uint4*)(Opart + ((size_t)i * SEQL + row) * (size_t)HID + col);
#pragma unroll
    for (int j = 0; j < 8; ++j) acc[j] += ls[i] * bf2f(X.h[j]);
  }
  union { uint4 u; u16 h[8]; } O;
#pragma unroll
  for (int j = 0; j < 8; ++j) O.h[j] = f2bf(acc[j] * inv);
  *(uint4*)(amrg + (size_t)row * 2048 + col) = O.u;
}

extern "C" void kernel_launch(void* const* d_in, const int* in_sizes, int n_in,
                              void* d_out, int out_size, void* d_ws, size_t ws_size,
                              hipStream_t stream) {
  (void)in_sizes; (void)n_in; (void)out_size; (void)ws_size;
  const float* hidden = (const float*)d_in[0];
  const float* q_cos = (const float*)d_in[2];
  const float* q_sin = (const float*)d_in[3];
  const float* qc_cos = (const float*)d_in[4];
  const float* qc_sin = (const float*)d_in[5];
  const float* k_cos = (const float*)d_in[6];
  const float* k_sin = (const float*)d_in[7];
  const float* Wq = (const float*)d_in[8];
  const float* Wk = (const float*)d_in[9];
  const float* Wv = (const float*)d_in[10];
  const float* Wo = (const float*)d_in[11];
  float* out = (float*)d_out;

  char* ws = (char*)d_ws;
  // fixed region
  u16* Wo_bf = (u16*)(ws + 0);                      //  8,388,608
  u16* qa    = (u16*)(ws + 8388608);                // 20,447,232
  u16* qb    = (u16*)(ws + 28835840);               // 13,631,488
  u16* qf    = (u16*)(ws + 42467328);               //  6,815,744
  u16* k_bf  = (u16*)(ws + 49283072);               //  5,111,808
  u16* vT    = (u16*)(ws + 54394880);               //  5,111,808
  char* BIG  = ws + 59506688;
  // BIG overlay, phase 1-3
  u16* h_bf  = (u16*)(BIG + 0);                     // 20,447,232
  u16* Wqkv  = (u16*)(BIG + 20447232);              // 12,582,912
  u16* q_tmp = (u16*)(BIG + 33030144);              // 20,447,232
  u16* k_tmp = (u16*)(BIG + 53477376);              //  5,111,808
  // BIG overlay, phase 4-5
  u16* Opart = (u16*)(BIG + 0);                     // 61,341,696 (3 slots)
  float* lse = (float*)(BIG + 61341696);            //    958,464
  u16* amrg  = qa;                                  // alias: qa dead after attn

  cvt_all_kernel<<<dim3(20224), dim3(256), 0, stream>>>(hidden, Wq, Wk, Wv, Wo, h_bf, Wqkv, Wo_bf);
  gemm_qkv<<<dim3(240), dim3(512), 0, stream>>>(h_bf, Wqkv, q_tmp, k_tmp, vT);
  rope_all_kernel<<<dim3(11232), dim3(256), 0, stream>>>(q_tmp, k_tmp, qa, qb, qf, k_bf,
                                                         q_cos, q_sin, qc_cos, qc_sin, k_cos, k_sin);
  attn_kernel<<<dim3(672), dim3(512), 0, stream>>>(qa, qb, qf, k_bf, vT, Opart, lse);
  merge_kernel<<<dim3(SEQL), dim3(256), 0, stream>>>(Opart, lse, amrg);
  gemm_o<<<dim3(624), 256, 0, stream>>>(amrg, Wo_bf, out);
}

// Round 19
// 501.936 us; speedup vs baseline: 1.7433x; 1.0316x over previous
//
#include <hip/hip_runtime.h>

typedef unsigned short u16;
typedef unsigned int u32;
typedef __attribute__((ext_vector_type(8))) __bf16 bf16x8;
typedef __attribute__((ext_vector_type(4))) float f32x4;
typedef __attribute__((ext_vector_type(16))) float f32x16;

#define CLEN 1664
#define SEQL 4992
#define NHEADS 16
#define HD 128
#define HID 2048
#define KVD 512
#define SCALE 0.08838834764831845f
#define SCLOG2E 0.12752615142058843f  // SCALE * log2(e)

__device__ __forceinline__ u16 f2bf(float f) {
  union { float f; u32 u; } v; v.f = f;
  u32 u = v.u;
  return (u16)((u + 0x7FFFu + ((u >> 16) & 1u)) >> 16);
}
__device__ __forceinline__ float bf2f(u16 h) {
  union { u32 u; float f; } v; v.u = (u32)h << 16;
  return v.f;
}
__device__ __forceinline__ f32x4 mfma16(bf16x8 a, bf16x8 b, f32x4 c) {
  return __builtin_amdgcn_mfma_f32_16x16x32_bf16(a, b, c, 0, 0, 0);
}
__device__ __forceinline__ f32x16 mfma32(bf16x8 a, bf16x8 b, f32x16 c) {
  return __builtin_amdgcn_mfma_f32_32x32x16_bf16(a, b, c, 0, 0, 0);
}
__device__ __forceinline__ u32 cvtpk(float lo, float hi) {
  u32 r;
  asm("v_cvt_pk_bf16_f32 %0, %1, %2" : "=v"(r) : "v"(lo), "v"(hi));
  return r;
}
__device__ __forceinline__ float exp2v(float x) {
  float r;
  asm("v_exp_f32 %0, %1" : "=v"(r) : "v"(x));
  return r;
}
__device__ __forceinline__ void gload_lds16(const u16* g, u16* l) {
  __builtin_amdgcn_global_load_lds((const __attribute__((address_space(1))) void*)g,
                                   (__attribute__((address_space(3))) void*)l, 16, 0, 0);
}

// ---------------- fused f32 -> bf16 convert (5 regions, 1 launch) ----------
#define CVT_Q0 2555904   // hidden  (10223616/4)
#define CVT_Q1 1048576   // Wq
#define CVT_Q2 262144    // Wk
#define CVT_Q3 262144    // Wv
#define CVT_Q4 1048576   // Wo
__device__ __forceinline__ void cvt4(const float* s, u16* d, int q) {
  float4 v = *(const float4*)(s + (size_t)q * 4);
  uint2 p;
  p.x = (u32)f2bf(v.x) | ((u32)f2bf(v.y) << 16);
  p.y = (u32)f2bf(v.z) | ((u32)f2bf(v.w) << 16);
  *(uint2*)(d + (size_t)q * 4) = p;
}
__global__ void cvt_all_kernel(const float* __restrict__ hidden, const float* __restrict__ Wq,
                               const float* __restrict__ Wk, const float* __restrict__ Wv,
                               const float* __restrict__ Wo, u16* __restrict__ h_bf,
                               u16* __restrict__ Wqkv, u16* __restrict__ Wo_bf) {
  int q = blockIdx.x * blockDim.x + threadIdx.x;
  if (q < CVT_Q0) { cvt4(hidden, h_bf, q); return; }
  q -= CVT_Q0;
  if (q < CVT_Q1) { cvt4(Wq, Wqkv, q); return; }
  q -= CVT_Q1;
  if (q < CVT_Q2) { cvt4(Wk, Wqkv + 2048 * 2048, q); return; }
  q -= CVT_Q2;
  if (q < CVT_Q3) { cvt4(Wv, Wqkv + 2560 * 2048, q); return; }
  q -= CVT_Q3;
  if (q < CVT_Q4) cvt4(Wo, Wo_bf, q);
}

// ---------------- K-only RoPE (Q rope is fused into attn) ------------------
#define RPK_N 319488   // 4992 * 64 groups of 8
__global__ void rope_k_kernel(const u16* __restrict__ k_tmp, u16* __restrict__ k_bf,
                              const float* __restrict__ k_cos, const float* __restrict__ k_sin) {
  int o = blockIdx.x * blockDim.x + threadIdx.x;
  if (o >= RPK_N) return;
  const int r = o >> 6, col = (o & 63) * 8;
  const int dh = col & 127;
  const bool hih = dh >= 64;
  const u16* rowp = k_tmp + (size_t)r * 512;
  union { uint4 u; u16 h[8]; } X, P, O;
  X.u = *(const uint4*)(rowp + col);
  P.u = *(const uint4*)(rowp + col + (hih ? -64 : 64));
  const float* cp = k_cos + r * 128 + dh;
  const float* sp = k_sin + r * 128 + dh;
#pragma unroll
  for (int j = 0; j < 8; ++j) {
    float v = bf2f(X.h[j]) * cp[j] + (hih ? bf2f(P.h[j]) : -bf2f(P.h[j])) * sp[j];
    O.h[j] = f2bf(v);
  }
  *(uint4*)(k_bf + (size_t)r * 512 + col) = O.u;
}

// ---------------- fused QKV GEMM (128^2, 1D grid, XCD-swizzled) ------------
__global__ __launch_bounds__(256) void gemm_qkv(const u16* __restrict__ A, const u16* __restrict__ B,
                                                u16* __restrict__ q_tmp, u16* __restrict__ k_tmp,
                                                u16* __restrict__ vT) {
  __shared__ __align__(16) u16 Al[128 * 64];
  __shared__ __align__(16) u16 Bl[128 * 64];
  const int K = HID;
  const int t = threadIdx.x;
  const int lane = t & 63, wid = t >> 6;
  const int g = lane >> 4, c = lane & 15;
  const int wr = wid >> 1, wc = wid & 1;
  const int bid = blockIdx.x;                      // 936 = 39 x 24, 936%8==0
  const int wg = (bid & 7) * 117 + (bid >> 3);     // XCD-contiguous chunks
  const int m0 = (wg % 39) * 128, n0 = (wg / 39) * 128;

  f32x4 acc[4][4];
#pragma unroll
  for (int m = 0; m < 4; ++m)
#pragma unroll
    for (int n = 0; n < 4; ++n) acc[m][n] = (f32x4){0.f, 0.f, 0.f, 0.f};

  const int scol = (t & 7) * 8;
  for (int k0 = 0; k0 < K; k0 += 64) {
    __syncthreads();
#pragma unroll
    for (int i = 0; i < 4; ++i) {
      const int r = i * 32 + (t >> 3);
      gload_lds16(A + (size_t)(m0 + r) * K + k0 + scol, Al + i * 2048 + wid * 512);
      gload_lds16(B + (size_t)(n0 + r) * K + k0 + scol, Bl + i * 2048 + wid * 512);
    }
    __syncthreads();
#pragma unroll
    for (int kk = 0; kk < 2; ++kk) {
      bf16x8 af[4], bfr[4];
#pragma unroll
      for (int m = 0; m < 4; ++m)
        af[m] = *(const bf16x8*)(Al + (wr * 64 + m * 16 + c) * 64 + kk * 32 + g * 8);
#pragma unroll
      for (int n = 0; n < 4; ++n)
        bfr[n] = *(const bf16x8*)(Bl + (wc * 64 + n * 16 + c) * 64 + kk * 32 + g * 8);
#pragma unroll
      for (int m = 0; m < 4; ++m)
#pragma unroll
        for (int n = 0; n < 4; ++n)
          acc[m][n] = mfma16(af[m], bfr[n], acc[m][n]);
    }
  }
#pragma unroll
  for (int m = 0; m < 4; ++m)
#pragma unroll
    for (int n = 0; n < 4; ++n)
#pragma unroll
      for (int j = 0; j < 4; ++j) {
        const int row = m0 + wr * 64 + m * 16 + 4 * g + j;
        const int col = n0 + wc * 64 + n * 16 + c;
        const float v = acc[m][n][j];
        if (n0 < 2048)       q_tmp[(size_t)row * 2048 + col] = f2bf(v);
        else if (n0 < 2560)  k_tmp[(size_t)row * 512 + (col - 2048)] = f2bf(v);
        else                 vT[(size_t)(col - 2560) * SEQL + row] = f2bf(v);
      }
}

// ---------------- O-projection GEMM (1D grid, XCD-swizzled), f32 out -------
__global__ __launch_bounds__(256) void gemm_o(const u16* __restrict__ A, const u16* __restrict__ B,
                                              float* __restrict__ Cf) {
  __shared__ __align__(16) u16 Al[128 * 64];
  __shared__ __align__(16) u16 Bl[128 * 64];
  const int K = HID, N = HID;
  const int t = threadIdx.x;
  const int lane = t & 63, wid = t >> 6;
  const int g = lane >> 4, c = lane & 15;
  const int wr = wid >> 1, wc = wid & 1;
  const int bid = blockIdx.x;                      // 624 = 39 x 16, 624%8==0
  const int wg = (bid & 7) * 78 + (bid >> 3);
  const int m0 = (wg % 39) * 128, n0 = (wg / 39) * 128;

  f32x4 acc[4][4];
#pragma unroll
  for (int m = 0; m < 4; ++m)
#pragma unroll
    for (int n = 0; n < 4; ++n) acc[m][n] = (f32x4){0.f, 0.f, 0.f, 0.f};

  const int scol = (t & 7) * 8;
  for (int k0 = 0; k0 < K; k0 += 64) {
    __syncthreads();
#pragma unroll
    for (int i = 0; i < 4; ++i) {
      const int r = i * 32 + (t >> 3);
      gload_lds16(A + (size_t)(m0 + r) * K + k0 + scol, Al + i * 2048 + wid * 512);
      gload_lds16(B + (size_t)(n0 + r) * K + k0 + scol, Bl + i * 2048 + wid * 512);
    }
    __syncthreads();
#pragma unroll
    for (int kk = 0; kk < 2; ++kk) {
      bf16x8 af[4], bfr[4];
#pragma unroll
      for (int m = 0; m < 4; ++m)
        af[m] = *(const bf16x8*)(Al + (wr * 64 + m * 16 + c) * 64 + kk * 32 + g * 8);
#pragma unroll
      for (int n = 0; n < 4; ++n)
        bfr[n] = *(const bf16x8*)(Bl + (wc * 64 + n * 16 + c) * 64 + kk * 32 + g * 8);
#pragma unroll
      for (int m = 0; m < 4; ++m)
#pragma unroll
        for (int n = 0; n < 4; ++n)
          acc[m][n] = mfma16(af[m], bfr[n], acc[m][n]);
    }
  }
#pragma unroll
  for (int m = 0; m < 4; ++m)
#pragma unroll
    for (int n = 0; n < 4; ++n)
#pragma unroll
      for (int j = 0; j < 4; ++j) {
        const int row = m0 + wr * 64 + m * 16 + 4 * g + j;
        const int col = n0 + wc * 64 + n * 16 + c;
        Cf[(size_t)row * N + col] = acc[m][n][j];
      }
}

// ---------------- static-schedule partial-attention kernel ------------------
// r12-proven structure; Q-RoPE fused into the Q-load (rotate-half pairing is
// lane-local in the swapped layout: fragment ck pairs with ck^4).
__global__ __launch_bounds__(512, 4) void attn_kernel(
    const u16* __restrict__ q_tmp, const u16* __restrict__ kbf, const u16* __restrict__ vT,
    const float* __restrict__ q_cos, const float* __restrict__ q_sin,
    const float* __restrict__ qc_cos, const float* __restrict__ qc_sin,
    u16* __restrict__ Opart, float* __restrict__ lseout) {
  __shared__ __align__(16) u16 smem[2 * 16384];  // [buf][K 8192 | V 8192] u16

  const int t = threadIdx.x, wid = t >> 6, lane = t & 63;
  const int ql = lane & 31, hi = lane >> 5;
  const int ksr = t >> 4, ksc = t & 15;  // K staging: row ksr+32i
  const int vsr = t >> 3, vsc = t & 7;   // V staging: row vsr+64i

  // ---- static part decode: fulls first (26 tiles), then causal qb6..qb0 ----
  const int b = blockIdx.x;
  int chunk, seg, qb, head;
  if (b < 336) {
    head = b & 15;
    const int f = b >> 4;          // 0..20
    const int part = f / 7; qb = f % 7;
    chunk = (part == 0) ? 1 : 2;
    seg = (part == 2) ? 1 : 0;
  } else {
    const int i = b - 336;         // 0..335
    qb = 6 - i / 48;               // 48 parts per qb band
    const int j = i % 48;
    head = j & 15; chunk = j >> 4; seg = chunk;
  }
  const bool causal = (seg == chunk);
  const int nt = causal ? ((qb == 6) ? 26 : (4 * qb + 4)) : 26;
  const int slot = causal ? 0 : ((chunk - seg == 1) ? 1 : 2);
  const int kvh = head >> 2;
  const int kvbase = seg * CLEN;
  const int qcb = qb * 256 + wid * 32;
  const int qpos = qcb + ql;
  const bool wact = qcb < CLEN;    // qb==6 upper waves idle

  // ---- Q load + fused RoPE (pre-scaled by SCALE*log2e) ----
  bf16x8 aq[8];
  {
    const float* ct = causal ? q_cos : qc_cos;
    const float* st = causal ? q_sin : qc_sin;
    const int pid = (causal || (chunk - seg == 1)) ? qpos : (CLEN - 1);
    const int qrow = wact ? (chunk * CLEN + qpos) : 0;
    const u16* qptr = q_tmp + (size_t)qrow * HID + head * HD + hi * 8;
    union { bf16x8 v; u16 h[8]; } xf[8];
#pragma unroll
    for (int ck = 0; ck < 8; ++ck) xf[ck].v = *(const bf16x8*)(qptr + ck * 16);
    const float* cb = ct + pid * 128 + hi * 8;
    const float* sb = st + pid * 128 + hi * 8;
#pragma unroll
    for (int ck = 0; ck < 8; ++ck) {
      union { bf16x8 v; u16 h[8]; } o;
      const int d0 = ck * 16;
      const float sgn = (ck < 4) ? -1.f : 1.f;
#pragma unroll
      for (int j = 0; j < 8; ++j) {
        float v = bf2f(xf[ck].h[j]) * cb[d0 + j] + sgn * bf2f(xf[ck ^ 4].h[j]) * sb[d0 + j];
        o.h[j] = f2bf(v * SCLOG2E);
      }
      aq[ck] = o.v;
    }
  }

  float l_r = 0.f;
  f32x16 oacc[4];
#pragma unroll
  for (int db = 0; db < 4; ++db)
#pragma unroll
    for (int r = 0; r < 16; ++r) oacc[db][r] = 0.f;

  auto stage = [&](int bb, int kt) {
    const int kv0 = kt * 64;
#pragma unroll
    for (int i = 0; i < 2; ++i) {
      const int rr = ksr + 32 * i;
      const int gs = ksc ^ (rr & 7);
      gload_lds16(kbf + (size_t)(kvbase + kv0 + rr) * KVD + kvh * HD + gs * 8,
                  smem + bb * 16384 + i * 4096 + wid * 512);
    }
#pragma unroll
    for (int i = 0; i < 2; ++i) {
      const int rr = vsr + 64 * i;
      const int gs = vsc ^ (rr & 7);
      gload_lds16(vT + (size_t)(kvh * HD + rr) * SEQL + kvbase + kv0 + gs * 8,
                  smem + bb * 16384 + 8192 + i * 4096 + wid * 512);
    }
  };

  stage(0, 0);
  int cur = 0;
  for (int kt = 0; kt < nt; ++kt) {
    if (kt + 1 < nt) {
      stage(cur ^ 1, kt + 1);
      asm volatile("s_waitcnt vmcnt(4)" ::: "memory");
    } else {
      asm volatile("s_waitcnt vmcnt(0)" ::: "memory");
    }
    __builtin_amdgcn_s_barrier();
    const int kv0 = kt * 64;
    const u16* Kb = smem + cur * 16384;
    const u16* Vb = smem + cur * 16384 + 8192;
#pragma unroll
    for (int s = 0; s < 2; ++s) {
      if (wact && !(causal && kv0 + 32 * s > qcb + 31)) {
        f32x16 sacc;
#pragma unroll
        for (int r = 0; r < 16; ++r) sacc[r] = 0.f;
        const int kr = 32 * s + ql;
        const int r7 = lane & 7;
        __builtin_amdgcn_s_setprio(1);
#pragma unroll
        for (int ck = 0; ck < 8; ++ck) {
          bf16x8 kb = *(const bf16x8*)(Kb + kr * 128 + (((2 * ck + hi) ^ r7) * 8));
          sacc = mfma32(kb, aq[ck], sacc);
        }
        __builtin_amdgcn_s_setprio(0);
        const int thr = qpos - kv0 - 32 * s - 4 * hi;
        float e[16];
        float rs = 0.f;
#pragma unroll
        for (int r = 0; r < 16; ++r) {
          const int crow_r = (r & 3) + 8 * (r >> 2);
          float ev = (causal && crow_r > thr) ? -1e30f : sacc[r];
          e[r] = exp2v(ev);
          rs += e[r];
        }
        rs += __shfl_xor(rs, 32);
        l_r += rs;
        u32 wp[8];
#pragma unroll
        for (int j2 = 0; j2 < 8; ++j2) wp[j2] = cvtpk(e[2 * j2], e[2 * j2 + 1]);
        __builtin_amdgcn_s_setprio(1);
#pragma unroll
        for (int ks = 0; ks < 2; ++ks) {
          union { uint4 u; bf16x8 v; } pa;
          pa.u.x = wp[4 * ks]; pa.u.y = wp[4 * ks + 1];
          pa.u.z = wp[4 * ks + 2]; pa.u.w = wp[4 * ks + 3];
          const int g4a = 8 * s + 4 * ks + hi;
          const int sw = (lane & 7) << 1;
#pragma unroll
          for (int db = 0; db < 4; ++db) {
            const int vrow = 32 * db + ql;
            const uint2 v0 = *(const uint2*)(Vb + vrow * 64 + ((g4a ^ sw) * 4));
            const uint2 v1 = *(const uint2*)(Vb + vrow * 64 + (((g4a + 2) ^ sw) * 4));
            union { uint4 u; bf16x8 v; } bv;
            bv.u.x = v0.x; bv.u.y = v0.y; bv.u.z = v1.x; bv.u.w = v1.y;
            oacc[db] = mfma32(pa.v, bv.v, oacc[db]);
          }
        }
        __builtin_amdgcn_s_setprio(0);
      }
    }
    __builtin_amdgcn_s_barrier();
    cur ^= 1;
  }
  // ---- epilogue: scale, transpose via LDS (K/V bufs are dead), 256B rows ---
  if (wact) {
    const float linv = 1.0f / l_r;
    u16* scr = smem + wid * 4096;  // per-wave 32x128 u16 scratch
#pragma unroll
    for (int r = 0; r < 16; ++r) {
      const int rrow = (r & 3) + 8 * (r >> 2) + 4 * hi;
      const float li = __shfl(linv, rrow);
#pragma unroll
      for (int db = 0; db < 4; ++db)
        scr[rrow * 128 + db * 32 + ql] = f2bf(oacc[db][r] * li);
    }
    asm volatile("s_waitcnt lgkmcnt(0)" ::: "memory");
    const int rcol = lane & 15;
#pragma unroll
    for (int p = 0; p < 8; ++p) {
      const int row = p * 4 + (lane >> 4);
      uint4 v = *(const uint4*)(scr + row * 128 + rcol * 8);
      const size_t grow = (size_t)(chunk * CLEN + qcb + row);
      *(uint4*)(Opart + ((size_t)slot * SEQL + grow) * HID + head * HD + rcol * 8) = v;
    }
    if (hi == 0)
      lseout[((size_t)slot * NHEADS + head) * SEQL + chunk * CLEN + qcb + ql] = __logf(l_r);
  }
}

// ---------------- merge partials (softmax over lse) ------------------------
__global__ void merge_kernel(const u16* __restrict__ Opart, const float* __restrict__ lse,
                             u16* __restrict__ amrg) {
  const int idx = blockIdx.x * blockDim.x + threadIdx.x;  // 4992*256 threads
  const int row = idx >> 8;
  const int col = (idx & 255) * 8;
  const int head = col >> 7;
  const int np = row / CLEN + 1;
  float ls[3];
  float mx = -1e30f;
  for (int i = 0; i < np; ++i) {
    ls[i] = lse[((size_t)i * NHEADS + head) * SEQL + row];
    mx = fmaxf(mx, ls[i]);
  }
  float wsum = 0.f;
  for (int i = 0; i < np; ++i) { ls[i] = __expf(ls[i] - mx); wsum += ls[i]; }
  const float inv = 1.0f / wsum;
  float acc[8];
#pragma unroll
  for (int j = 0; j < 8; ++j) acc[j] = 0.f;
  for (int i = 0; i < np; ++i) {
    union { uint4 u; u16 h[8]; } X;
    X.u = *(const uint4*)(Opart + ((size_t)i * SEQL + row) * (size_t)HID + col);
#pragma unroll
    for (int j = 0; j < 8; ++j) acc[j] += ls[i] * bf2f(X.h[j]);
  }
  union { uint4 u; u16 h[8]; } O;
#pragma unroll
  for (int j = 0; j < 8; ++j) O.h[j] = f2bf(acc[j] * inv);
  *(uint4*)(amrg + (size_t)row * 2048 + col) = O.u;
}

extern "C" void kernel_launch(void* const* d_in, const int* in_sizes, int n_in,
                              void* d_out, int out_size, void* d_ws, size_t ws_size,
                              hipStream_t stream) {
  (void)in_sizes; (void)n_in; (void)out_size; (void)ws_size;
  const float* hidden = (const float*)d_in[0];
  const float* q_cos = (const float*)d_in[2];
  const float* q_sin = (const float*)d_in[3];
  const float* qc_cos = (const float*)d_in[4];
  const float* qc_sin = (const float*)d_in[5];
  const float* k_cos = (const float*)d_in[6];
  const float* k_sin = (const float*)d_in[7];
  const float* Wq = (const float*)d_in[8];
  const float* Wk = (const float*)d_in[9];
  const float* Wv = (const float*)d_in[10];
  const float* Wo = (const float*)d_in[11];
  float* out = (float*)d_out;

  char* ws = (char*)d_ws;
  // fixed region (q_tmp lives OUTSIDE the BIG overlay: attn reads it while
  // Opart occupies the overlay)
  u16* Wo_bf = (u16*)(ws + 0);                      //  8,388,608
  u16* q_tmp = (u16*)(ws + 8388608);                // 20,447,232
  u16* k_bf  = (u16*)(ws + 28835840);               //  5,111,808
  u16* vT    = (u16*)(ws + 33947648);               //  5,111,808
  char* BIG  = ws + 39059456;
  // BIG overlay, phase 1-3
  u16* h_bf  = (u16*)(BIG + 0);                     // 20,447,232
  u16* Wqkv  = (u16*)(BIG + 20447232);              // 12,582,912
  u16* k_tmp = (u16*)(BIG + 33030144);              //  5,111,808
  // BIG overlay, phase 4-5
  u16* Opart = (u16*)(BIG + 0);                     // 61,341,696 (3 slots)
  float* lse = (float*)(BIG + 61341696);            //    958,464
  u16* amrg  = q_tmp;                               // alias: q_tmp dead after attn

  cvt_all_kernel<<<dim3(20224), dim3(256), 0, stream>>>(hidden, Wq, Wk, Wv, Wo, h_bf, Wqkv, Wo_bf);
  gemm_qkv<<<dim3(936), 256, 0, stream>>>(h_bf, Wqkv, q_tmp, k_tmp, vT);
  rope_k_kernel<<<dim3(1248), dim3(256), 0, stream>>>(k_tmp, k_bf, k_cos, k_sin);
  attn_kernel<<<dim3(672), dim3(512), 0, stream>>>(q_tmp, k_bf, vT, q_cos, q_sin,
                                                   qc_cos, qc_sin, Opart, lse);
  merge_kernel<<<dim3(SEQL), dim3(256), 0, stream>>>(Opart, lse, amrg);
  gemm_o<<<dim3(624), 256, 0, stream>>>(amrg, Wo_bf, out);
}

// Round 21
// 492.341 us; speedup vs baseline: 1.7773x; 1.0195x over previous
//
#include <hip/hip_runtime.h>

typedef unsigned short u16;
typedef unsigned int u32;
typedef __attribute__((ext_vector_type(8))) __bf16 bf16x8;
typedef __attribute__((ext_vector_type(4))) float f32x4;
typedef __attribute__((ext_vector_type(16))) float f32x16;

#define CLEN 1664
#define SEQL 4992
#define NHEADS 16
#define HD 128
#define HID 2048
#define KVD 512
#define SCALE 0.08838834764831845f
#define SCLOG2E 0.12752615142058843f  // SCALE * log2(e)

__device__ __forceinline__ u16 f2bf(float f) {
  union { float f; u32 u; } v; v.f = f;
  u32 u = v.u;
  return (u16)((u + 0x7FFFu + ((u >> 16) & 1u)) >> 16);
}
__device__ __forceinline__ float bf2f(u16 h) {
  union { u32 u; float f; } v; v.u = (u32)h << 16;
  return v.f;
}
__device__ __forceinline__ f32x4 mfma16(bf16x8 a, bf16x8 b, f32x4 c) {
  return __builtin_amdgcn_mfma_f32_16x16x32_bf16(a, b, c, 0, 0, 0);
}
__device__ __forceinline__ f32x16 mfma32(bf16x8 a, bf16x8 b, f32x16 c) {
  return __builtin_amdgcn_mfma_f32_32x32x16_bf16(a, b, c, 0, 0, 0);
}
__device__ __forceinline__ u32 cvtpk(float lo, float hi) {
  u32 r;
  asm("v_cvt_pk_bf16_f32 %0, %1, %2" : "=v"(r) : "v"(lo), "v"(hi));
  return r;
}
__device__ __forceinline__ float exp2v(float x) {
  float r;
  asm("v_exp_f32 %0, %1" : "=v"(r) : "v"(x));
  return r;
}
__device__ __forceinline__ void gload_lds16(const u16* g, u16* l) {
  __builtin_amdgcn_global_load_lds((const __attribute__((address_space(1))) void*)g,
                                   (__attribute__((address_space(3))) void*)l, 16, 0, 0);
}

// ---------------- fused f32 -> bf16 convert + rope-table pack (1 launch) ---
#define CVT_Q0 2555904   // hidden  (10223616/4)
#define CVT_Q1 1048576   // Wq
#define CVT_Q2 262144    // Wk
#define CVT_Q3 262144    // Wv
#define CVT_Q4 1048576   // Wo
#define CVT_Q5 53248     // one packed rope table: 1664 rows x 32 groups of 8
__device__ __forceinline__ void cvt4(const float* s, u16* d, int q) {
  float4 v = *(const float4*)(s + (size_t)q * 4);
  uint2 p;
  p.x = (u32)f2bf(v.x) | ((u32)f2bf(v.y) << 16);
  p.y = (u32)f2bf(v.z) | ((u32)f2bf(v.w) << 16);
  *(uint2*)(d + (size_t)q * 4) = p;
}
__device__ __forceinline__ void pack8(const float* s, u16* d) {
  float4 v0 = *(const float4*)s, v1 = *(const float4*)(s + 4);
  uint4 o;
  o.x = (u32)f2bf(v0.x) | ((u32)f2bf(v0.y) << 16);
  o.y = (u32)f2bf(v0.z) | ((u32)f2bf(v0.w) << 16);
  o.z = (u32)f2bf(v1.x) | ((u32)f2bf(v1.y) << 16);
  o.w = (u32)f2bf(v1.z) | ((u32)f2bf(v1.w) << 16);
  *(uint4*)d = o;
}
__global__ void cvt_all_kernel(const float* __restrict__ hidden, const float* __restrict__ Wq,
                               const float* __restrict__ Wk, const float* __restrict__ Wv,
                               const float* __restrict__ Wo, const float* __restrict__ q_cos,
                               const float* __restrict__ q_sin, const float* __restrict__ qc_cos,
                               const float* __restrict__ qc_sin, u16* __restrict__ h_bf,
                               u16* __restrict__ Wqkv, u16* __restrict__ Wo_bf,
                               u16* __restrict__ qt_a, u16* __restrict__ qt_c) {
  int q = blockIdx.x * blockDim.x + threadIdx.x;
  if (q < CVT_Q0) { cvt4(hidden, h_bf, q); return; }
  q -= CVT_Q0;
  if (q < CVT_Q1) { cvt4(Wq, Wqkv, q); return; }
  q -= CVT_Q1;
  if (q < CVT_Q2) { cvt4(Wk, Wqkv + 2048 * 2048, q); return; }
  q -= CVT_Q2;
  if (q < CVT_Q3) { cvt4(Wv, Wqkv + 2560 * 2048, q); return; }
  q -= CVT_Q3;
  if (q < CVT_Q4) { cvt4(Wo, Wo_bf, q); return; }
  q -= CVT_Q4;
  if (q < 2 * CVT_Q5) {
    const int tab = q / CVT_Q5, rem = q % CVT_Q5;
    const int pid = rem >> 5, jj = rem & 31;
    const float* cs = (tab == 0) ? q_cos : qc_cos;
    const float* sn = (tab == 0) ? q_sin : qc_sin;
    const float* src = (jj < 16) ? (cs + pid * 128 + jj * 8) : (sn + pid * 128 + (jj - 16) * 8);
    u16* dst = ((tab == 0) ? qt_a : qt_c) + pid * 256 + jj * 8;
    pack8(src, dst);
  }
}

// ---------------- K-only RoPE (Q rope is fused into attn) ------------------
#define RPK_N 319488   // 4992 * 64 groups of 8
__global__ void rope_k_kernel(const u16* __restrict__ k_tmp, u16* __restrict__ k_bf,
                              const float* __restrict__ k_cos, const float* __restrict__ k_sin) {
  int o = blockIdx.x * blockDim.x + threadIdx.x;
  if (o >= RPK_N) return;
  const int r = o >> 6, col = (o & 63) * 8;
  const int dh = col & 127;
  const bool hih = dh >= 64;
  const u16* rowp = k_tmp + (size_t)r * 512;
  union { uint4 u; u16 h[8]; } X, P, O;
  X.u = *(const uint4*)(rowp + col);
  P.u = *(const uint4*)(rowp + col + (hih ? -64 : 64));
  const float* cp = k_cos + r * 128 + dh;
  const float* sp = k_sin + r * 128 + dh;
#pragma unroll
  for (int j = 0; j < 8; ++j) {
    float v = bf2f(X.h[j]) * cp[j] + (hih ? bf2f(P.h[j]) : -bf2f(P.h[j])) * sp[j];
    O.h[j] = f2bf(v);
  }
  *(uint4*)(k_bf + (size_t)r * 512 + col) = O.u;
}

// ---------------- fused QKV GEMM (128^2, 1D grid, XCD-swizzled) ------------
__global__ __launch_bounds__(256) void gemm_qkv(const u16* __restrict__ A, const u16* __restrict__ B,
                                                u16* __restrict__ q_tmp, u16* __restrict__ k_tmp,
                                                u16* __restrict__ vT) {
  __shared__ __align__(16) u16 Al[128 * 64];
  __shared__ __align__(16) u16 Bl[128 * 64];
  const int K = HID;
  const int t = threadIdx.x;
  const int lane = t & 63, wid = t >> 6;
  const int g = lane >> 4, c = lane & 15;
  const int wr = wid >> 1, wc = wid & 1;
  const int bid = blockIdx.x;                      // 936 = 39 x 24, 936%8==0
  const int wg = (bid & 7) * 117 + (bid >> 3);     // XCD-contiguous chunks
  const int m0 = (wg % 39) * 128, n0 = (wg / 39) * 128;

  f32x4 acc[4][4];
#pragma unroll
  for (int m = 0; m < 4; ++m)
#pragma unroll
    for (int n = 0; n < 4; ++n) acc[m][n] = (f32x4){0.f, 0.f, 0.f, 0.f};

  const int scol = (t & 7) * 8;
  for (int k0 = 0; k0 < K; k0 += 64) {
    __syncthreads();
#pragma unroll
    for (int i = 0; i < 4; ++i) {
      const int r = i * 32 + (t >> 3);
      gload_lds16(A + (size_t)(m0 + r) * K + k0 + scol, Al + i * 2048 + wid * 512);
      gload_lds16(B + (size_t)(n0 + r) * K + k0 + scol, Bl + i * 2048 + wid * 512);
    }
    __syncthreads();
#pragma unroll
    for (int kk = 0; kk < 2; ++kk) {
      bf16x8 af[4], bfr[4];
#pragma unroll
      for (int m = 0; m < 4; ++m)
        af[m] = *(const bf16x8*)(Al + (wr * 64 + m * 16 + c) * 64 + kk * 32 + g * 8);
#pragma unroll
      for (int n = 0; n < 4; ++n)
        bfr[n] = *(const bf16x8*)(Bl + (wc * 64 + n * 16 + c) * 64 + kk * 32 + g * 8);
#pragma unroll
      for (int m = 0; m < 4; ++m)
#pragma unroll
        for (int n = 0; n < 4; ++n)
          acc[m][n] = mfma16(af[m], bfr[n], acc[m][n]);
    }
  }
#pragma unroll
  for (int m = 0; m < 4; ++m)
#pragma unroll
    for (int n = 0; n < 4; ++n)
#pragma unroll
      for (int j = 0; j < 4; ++j) {
        const int row = m0 + wr * 64 + m * 16 + 4 * g + j;
        const int col = n0 + wc * 64 + n * 16 + c;
        const float v = acc[m][n][j];
        if (n0 < 2048)       q_tmp[(size_t)row * 2048 + col] = f2bf(v);
        else if (n0 < 2560)  k_tmp[(size_t)row * 512 + (col - 2048)] = f2bf(v);
        else                 vT[(size_t)(col - 2560) * SEQL + row] = f2bf(v);
      }
}

// ---------------- O-projection GEMM (1D grid, XCD-swizzled), f32 out -------
__global__ __launch_bounds__(256) void gemm_o(const u16* __restrict__ A, const u16* __restrict__ B,
                                              float* __restrict__ Cf) {
  __shared__ __align__(16) u16 Al[128 * 64];
  __shared__ __align__(16) u16 Bl[128 * 64];
  const int K = HID, N = HID;
  const int t = threadIdx.x;
  const int lane = t & 63, wid = t >> 6;
  const int g = lane >> 4, c = lane & 15;
  const int wr = wid >> 1, wc = wid & 1;
  const int bid = blockIdx.x;                      // 624 = 39 x 16, 624%8==0
  const int wg = (bid & 7) * 78 + (bid >> 3);
  const int m0 = (wg % 39) * 128, n0 = (wg / 39) * 128;

  f32x4 acc[4][4];
#pragma unroll
  for (int m = 0; m < 4; ++m)
#pragma unroll
    for (int n = 0; n < 4; ++n) acc[m][n] = (f32x4){0.f, 0.f, 0.f, 0.f};

  const int scol = (t & 7) * 8;
  for (int k0 = 0; k0 < K; k0 += 64) {
    __syncthreads();
#pragma unroll
    for (int i = 0; i < 4; ++i) {
      const int r = i * 32 + (t >> 3);
      gload_lds16(A + (size_t)(m0 + r) * K + k0 + scol, Al + i * 2048 + wid * 512);
      gload_lds16(B + (size_t)(n0 + r) * K + k0 + scol, Bl + i * 2048 + wid * 512);
    }
    __syncthreads();
#pragma unroll
    for (int kk = 0; kk < 2; ++kk) {
      bf16x8 af[4], bfr[4];
#pragma unroll
      for (int m = 0; m < 4; ++m)
        af[m] = *(const bf16x8*)(Al + (wr * 64 + m * 16 + c) * 64 + kk * 32 + g * 8);
#pragma unroll
      for (int n = 0; n < 4; ++n)
        bfr[n] = *(const bf16x8*)(Bl + (wc * 64 + n * 16 + c) * 64 + kk * 32 + g * 8);
#pragma unroll
      for (int m = 0; m < 4; ++m)
#pragma unroll
        for (int n = 0; n < 4; ++n)
          acc[m][n] = mfma16(af[m], bfr[n], acc[m][n]);
    }
  }
#pragma unroll
  for (int m = 0; m < 4; ++m)
#pragma unroll
    for (int n = 0; n < 4; ++n)
#pragma unroll
      for (int j = 0; j < 4; ++j) {
        const int row = m0 + wr * 64 + m * 16 + 4 * g + j;
        const int col = n0 + wc * 64 + n * 16 + c;
        Cf[(size_t)row * N + col] = acc[m][n][j];
      }
}

// ---------------- static-schedule partial-attention kernel ------------------
// r12-proven structure; Q-RoPE fused into the Q-load using packed bf16 tables.
// Chunk-0 causal parts (merge identity) write directly to amrg.
__global__ __launch_bounds__(512, 4) void attn_kernel(
    const u16* q_tmp, const u16* __restrict__ kbf, const u16* __restrict__ vT,
    const u16* __restrict__ qt_a, const u16* __restrict__ qt_c,
    u16* __restrict__ Opart, float* __restrict__ lseout, u16* amrg) {
  __shared__ __align__(16) u16 smem[2 * 16384];  // [buf][K 8192 | V 8192] u16

  const int t = threadIdx.x, wid = t >> 6, lane = t & 63;
  const int ql = lane & 31, hi = lane >> 5;
  const int ksr = t >> 4, ksc = t & 15;  // K staging: row ksr+32i
  const int vsr = t >> 3, vsc = t & 7;   // V staging: row vsr+64i

  // ---- static part decode: fulls first (26 tiles), then causal qb6..qb0 ----
  const int b = blockIdx.x;
  int chunk, seg, qb, head;
  if (b < 336) {
    head = b & 15;
    const int f = b >> 4;          // 0..20
    const int part = f / 7; qb = f % 7;
    chunk = (part == 0) ? 1 : 2;
    seg = (part == 2) ? 1 : 0;
  } else {
    const int i = b - 336;         // 0..335
    qb = 6 - i / 48;               // 48 parts per qb band
    const int j = i % 48;
    head = j & 15; chunk = j >> 4; seg = chunk;
  }
  const bool causal = (seg == chunk);
  const int nt = causal ? ((qb == 6) ? 26 : (4 * qb + 4)) : 26;
  const int slot = causal ? 0 : ((chunk - seg == 1) ? 1 : 2);
  const int kvh = head >> 2;
  const int kvbase = seg * CLEN;
  const int qcb = qb * 256 + wid * 32;
  const int qpos = qcb + ql;
  const bool wact = qcb < CLEN;    // qb==6 upper waves idle

  // ---- Q load + fused RoPE from packed bf16 tables (pre-scaled) ----
  bf16x8 aq[8];
  {
    const u16* tb = causal ? qt_a : qt_c;
    const int pid = (causal || (chunk - seg == 1)) ? qpos : (CLEN - 1);
    const int qrow = wact ? (chunk * CLEN + qpos) : 0;
    const u16* qptr = q_tmp + (size_t)qrow * HID + head * HD + hi * 8;
    const u16* cb16 = tb + pid * 256 + hi * 8;
    union { bf16x8 v; u16 h[8]; } xf[8];
#pragma unroll
    for (int ck = 0; ck < 8; ++ck) xf[ck].v = *(const bf16x8*)(qptr + ck * 16);
#pragma unroll
    for (int ck = 0; ck < 8; ++ck) {
      union { bf16x8 v; u16 h[8]; } cv, sv, o;
      cv.v = *(const bf16x8*)(cb16 + ck * 16);
      sv.v = *(const bf16x8*)(cb16 + 128 + ck * 16);
      const float sgn = (ck < 4) ? -1.f : 1.f;
#pragma unroll
      for (int j = 0; j < 8; ++j) {
        float v = bf2f(xf[ck].h[j]) * bf2f(cv.h[j]) + sgn * bf2f(xf[ck ^ 4].h[j]) * bf2f(sv.h[j]);
        o.h[j] = f2bf(v * SCLOG2E);
      }
      aq[ck] = o.v;
    }
  }

  float l_r = 0.f;
  f32x16 oacc[4];
#pragma unroll
  for (int db = 0; db < 4; ++db)
#pragma unroll
    for (int r = 0; r < 16; ++r) oacc[db][r] = 0.f;

  auto stage = [&](int bb, int kt) {
    const int kv0 = kt * 64;
#pragma unroll
    for (int i = 0; i < 2; ++i) {
      const int rr = ksr + 32 * i;
      const int gs = ksc ^ (rr & 7);
      gload_lds16(kbf + (size_t)(kvbase + kv0 + rr) * KVD + kvh * HD + gs * 8,
                  smem + bb * 16384 + i * 4096 + wid * 512);
    }
#pragma unroll
    for (int i = 0; i < 2; ++i) {
      const int rr = vsr + 64 * i;
      const int gs = vsc ^ (rr & 7);
      gload_lds16(vT + (size_t)(kvh * HD + rr) * SEQL + kvbase + kv0 + gs * 8,
                  smem + bb * 16384 + 8192 + i * 4096 + wid * 512);
    }
  };

  stage(0, 0);
  int cur = 0;
  for (int kt = 0; kt < nt; ++kt) {
    if (kt + 1 < nt) {
      stage(cur ^ 1, kt + 1);
      asm volatile("s_waitcnt vmcnt(4)" ::: "memory");
    } else {
      asm volatile("s_waitcnt vmcnt(0)" ::: "memory");
    }
    __builtin_amdgcn_s_barrier();
    const int kv0 = kt * 64;
    const u16* Kb = smem + cur * 16384;
    const u16* Vb = smem + cur * 16384 + 8192;
#pragma unroll
    for (int s = 0; s < 2; ++s) {
      if (wact && !(causal && kv0 + 32 * s > qcb + 31)) {
        f32x16 sacc;
#pragma unroll
        for (int r = 0; r < 16; ++r) sacc[r] = 0.f;
        const int kr = 32 * s + ql;
        const int r7 = lane & 7;
        __builtin_amdgcn_s_setprio(1);
#pragma unroll
        for (int ck = 0; ck < 8; ++ck) {
          bf16x8 kb = *(const bf16x8*)(Kb + kr * 128 + (((2 * ck + hi) ^ r7) * 8));
          sacc = mfma32(kb, aq[ck], sacc);
        }
        __builtin_amdgcn_s_setprio(0);
        const int thr = qpos - kv0 - 32 * s - 4 * hi;
        float e[16];
        float rs = 0.f;
#pragma unroll
        for (int r = 0; r < 16; ++r) {
          const int crow_r = (r & 3) + 8 * (r >> 2);
          float ev = (causal && crow_r > thr) ? -1e30f : sacc[r];
          e[r] = exp2v(ev);
          rs += e[r];
        }
        rs += __shfl_xor(rs, 32);
        l_r += rs;
        u32 wp[8];
#pragma unroll
        for (int j2 = 0; j2 < 8; ++j2) wp[j2] = cvtpk(e[2 * j2], e[2 * j2 + 1]);
        __builtin_amdgcn_s_setprio(1);
#pragma unroll
        for (int ks = 0; ks < 2; ++ks) {
          union { uint4 u; bf16x8 v; } pa;
          pa.u.x = wp[4 * ks]; pa.u.y = wp[4 * ks + 1];
          pa.u.z = wp[4 * ks + 2]; pa.u.w = wp[4 * ks + 3];
          const int g4a = 8 * s + 4 * ks + hi;
          const int sw = (lane & 7) << 1;
#pragma unroll
          for (int db = 0; db < 4; ++db) {
            const int vrow = 32 * db + ql;
            const uint2 v0 = *(const uint2*)(Vb + vrow * 64 + ((g4a ^ sw) * 4));
            const uint2 v1 = *(const uint2*)(Vb + vrow * 64 + (((g4a + 2) ^ sw) * 4));
            union { uint4 u; bf16x8 v; } bv;
            bv.u.x = v0.x; bv.u.y = v0.y; bv.u.z = v1.x; bv.u.w = v1.y;
            oacc[db] = mfma32(pa.v, bv.v, oacc[db]);
          }
        }
        __builtin_amdgcn_s_setprio(0);
      }
    }
    __builtin_amdgcn_s_barrier();
    cur ^= 1;
  }
  // ---- epilogue: scale, transpose via LDS; chunk0-causal goes straight to amrg
  if (wact) {
    const float linv = 1.0f / l_r;
    u16* scr = smem + wid * 4096;  // per-wave 32x128 u16 scratch
#pragma unroll
    for (int r = 0; r < 16; ++r) {
      const int rrow = (r & 3) + 8 * (r >> 2) + 4 * hi;
      const float li = __shfl(linv, rrow);
#pragma unroll
      for (int db = 0; db < 4; ++db)
        scr[rrow * 128 + db * 32 + ql] = f2bf(oacc[db][r] * li);
    }
    asm volatile("s_waitcnt lgkmcnt(0)" ::: "memory");
    const bool direct = causal && (chunk == 0);
    const int rcol = lane & 15;
#pragma unroll
    for (int p = 0; p < 8; ++p) {
      const int row = p * 4 + (lane >> 4);
      uint4 v = *(const uint4*)(scr + row * 128 + rcol * 8);
      const size_t grow = (size_t)(chunk * CLEN + qcb + row);
      u16* od = direct ? (amrg + grow * HID) : (Opart + ((size_t)slot * SEQL + grow) * HID);
      *(uint4*)(od + head * HD + rcol * 8) = v;
    }
    if (hi == 0 && !direct)
      lseout[((size_t)slot * NHEADS + head) * SEQL + chunk * CLEN + qcb + ql] = __logf(l_r);
  }
}

// ---------------- merge partials for rows >= CLEN (softmax over lse) -------
__global__ void merge_kernel(const u16* __restrict__ Opart, const float* __restrict__ lse,
                             u16* __restrict__ amrg) {
  const int idx = blockIdx.x * blockDim.x + threadIdx.x;  // 3328*256 threads
  const int row = CLEN + (idx >> 8);
  const int col = (idx & 255) * 8;
  const int head = col >> 7;
  const int np = row / CLEN + 1;
  float ls[3];
  float mx = -1e30f;
  for (int i = 0; i < np; ++i) {
    ls[i] = lse[((size_t)i * NHEADS + head) * SEQL + row];
    mx = fmaxf(mx, ls[i]);
  }
  float wsum = 0.f;
  for (int i = 0; i < np; ++i) { ls[i] = __expf(ls[i] - mx); wsum += ls[i]; }
  const float inv = 1.0f / wsum;
  float acc[8];
#pragma unroll
  for (int j = 0; j < 8; ++j) acc[j] = 0.f;
  for (int i = 0; i < np; ++i) {
    union { uint4 u; u16 h[8]; } X;
    X.u = *(const uint4*)(Opart + ((size_t)i * SEQL + row) * (size_t)HID + col);
#pragma unroll
    for (int j = 0; j < 8; ++j) acc[j] += ls[i] * bf2f(X.h[j]);
  }
  union { uint4 u; u16 h[8]; } O;
#pragma unroll
  for (int j = 0; j < 8; ++j) O.h[j] = f2bf(acc[j] * inv);
  *(uint4*)(amrg + (size_t)row * 2048 + col) = O.u;
}

extern "C" void kernel_launch(void* const* d_in, const int* in_sizes, int n_in,
                              void* d_out, int out_size, void* d_ws, size_t ws_size,
                              hipStream_t stream) {
  (void)in_sizes; (void)n_in; (void)out_size; (void)ws_size;
  const float* hidden = (const float*)d_in[0];
  const float* q_cos = (const float*)d_in[2];
  const float* q_sin = (const float*)d_in[3];
  const float* qc_cos = (const float*)d_in[4];
  const float* qc_sin = (const float*)d_in[5];
  const float* k_cos = (const float*)d_in[6];
  const float* k_sin = (const float*)d_in[7];
  const float* Wq = (const float*)d_in[8];
  const float* Wk = (const float*)d_in[9];
  const float* Wv = (const float*)d_in[10];
  const float* Wo = (const float*)d_in[11];
  float* out = (float*)d_out;

  char* ws = (char*)d_ws;
  // fixed region (q_tmp survives into attn; amrg aliases it afterwards)
  u16* Wo_bf = (u16*)(ws + 0);                      //  8,388,608
  u16* q_tmp = (u16*)(ws + 8388608);                // 20,447,232
  u16* k_bf  = (u16*)(ws + 28835840);               //  5,111,808
  u16* vT    = (u16*)(ws + 33947648);               //  5,111,808
  u16* qt_a  = (u16*)(ws + 39059456);               //    851,968
  u16* qt_c  = (u16*)(ws + 39911424);               //    851,968
  char* BIG  = ws + 40763392;
  // BIG overlay, phase 1-3
  u16* h_bf  = (u16*)(BIG + 0);                     // 20,447,232
  u16* Wqkv  = (u16*)(BIG + 20447232);              // 12,582,912
  u16* k_tmp = (u16*)(BIG + 33030144);              //  5,111,808
  // BIG overlay, phase 4-5
  u16* Opart = (u16*)(BIG + 0);                     // 61,341,696 (3 slots)
  float* lse = (float*)(BIG + 61341696);            //    958,464
  u16* amrg  = q_tmp;                               // alias: see attn epilogue proof

  cvt_all_kernel<<<dim3(20640), dim3(256), 0, stream>>>(hidden, Wq, Wk, Wv, Wo,
                                                        q_cos, q_sin, qc_cos, qc_sin,
                                                        h_bf, Wqkv, Wo_bf, qt_a, qt_c);
  gemm_qkv<<<dim3(936), 256, 0, stream>>>(h_bf, Wqkv, q_tmp, k_tmp, vT);
  rope_k_kernel<<<dim3(1248), dim3(256), 0, stream>>>(k_tmp, k_bf, k_cos, k_sin);
  attn_kernel<<<dim3(672), dim3(512), 0, stream>>>(q_tmp, k_bf, vT, qt_a, qt_c,
                                                   Opart, lse, amrg);
  merge_kernel<<<dim3(3328), dim3(256), 0, stream>>>(Opart, lse, amrg);
  gemm_o<<<dim3(624), 256, 0, stream>>>(amrg, Wo_bf, out);
}